// Round 11
// baseline (579.655 us; speedup 1.0000x reference)
//
#include <hip/hip_runtime.h>
#include <hip/hip_bf16.h>
#include <hip/hip_cooperative_groups.h>
#include <cstddef>

namespace cg = cooperative_groups;

#define NN 100000
#define NE 1600000
#define NG 2000
#define NS 40
#define INF 64
#define F 128
#define FFN_DIM 1024
#define NB 782            // ceil(100000/128) buckets of 128 nodes
#define BCAP 3072         // fixed bucket capacity (mean 2048, sigma 45 -> 19+ sigma margin)
#define SC_BLOCKS 512
#define SC_CHUNK 3125     // 512*3125 = 1.6M edges exactly
#define KSPLIT 8

using bf16 = __hip_bfloat16;
typedef __attribute__((ext_vector_type(8))) short short8;
typedef __attribute__((ext_vector_type(4))) float f32x4;
typedef __attribute__((ext_vector_type(2))) float f32x2;

__device__ __forceinline__ short f2bs(float f){
    union { bf16 b; short s; } u; u.b = __float2bfloat16(f); return u.s;
}
__device__ __forceinline__ unsigned int pk2(float a, float b){
    return (unsigned int)(unsigned short)f2bs(a) | ((unsigned int)(unsigned short)f2bs(b) << 16);
}

// ================= cooperative front: init + scatter + sort (3 dispatches -> 1) =================
__global__ __launch_bounds__(1024) void k_front(int* __restrict__ bcursor, const int* __restrict__ ei,
                                                int* __restrict__ ebuf, int* __restrict__ cnt,
                                                float* __restrict__ dinv, int* __restrict__ nstart,
                                                int* __restrict__ ebuf2,
                                                const float* __restrict__ Wq, const float* __restrict__ Wk,
                                                const float* __restrict__ Wv, const float* __restrict__ W1,
                                                const float* __restrict__ W2, const float* __restrict__ Wg,
                                                unsigned short* __restrict__ Wqb, unsigned short* __restrict__ Wkb,
                                                unsigned short* __restrict__ Wvb, unsigned short* __restrict__ W1b,
                                                unsigned short* __restrict__ W2b, unsigned short* __restrict__ Wgb){
    cg::grid_group grid = cg::this_grid();
    __shared__ int lh[NB];
    __shared__ int lb[NB];
    __shared__ int s_s[128];
    __shared__ int s_lcur[128];
    __shared__ int sorted[BCAP];
    int t = threadIdx.x;
    int gt = blockIdx.x*1024 + t;
    int gstride = gridDim.x*1024;

    // ---- stage 0: bcursor init + weight tables -> transposed bf16 [n][k] ----
    for (int i=gt; i<NB; i+=gstride) bcursor[i] = i*BCAP;
    for (int i=gt; i<16384; i+=gstride){
        int k = i>>7, n = i&127;
        Wqb[n*128+k] = (unsigned short)f2bs(Wq[(size_t)k*F+n]);
        Wkb[n*128+k] = (unsigned short)f2bs(Wk[(size_t)k*F+n]);
        Wvb[n*128+k] = (unsigned short)f2bs(Wv[(size_t)k*F+n]);
        Wgb[n*128+k] = (unsigned short)f2bs(Wg[(size_t)k*F+n]);
    }
    for (int i=gt; i<131072; i+=gstride){
        int k = i>>10, n = i&1023;
        W1b[(size_t)n*128+k] = (unsigned short)f2bs(W1[(size_t)k*FFN_DIM+n]);
    }
    for (int i=gt; i<131072; i+=gstride){
        int n = i>>10, k = i&1023;
        W2b[(size_t)n*1024+k] = (unsigned short)f2bs(W2[(size_t)k*F+n]);
    }
    grid.sync();

    // ---- stage 1: binned scatter (512 chunks over blocks) ----
    for (int chunk = blockIdx.x; chunk < SC_BLOCKS; chunk += gridDim.x){
        int base = chunk * SC_CHUNK;
        for (int b=t; b<NB; b+=1024) lh[b] = 0;
        __syncthreads();
        int rr[4], cc[4];
        #pragma unroll
        for (int q=0;q<4;q++){
            int i = t + q*1024;
            bool v = (i < SC_CHUNK);
            int idx = v ? (base + i) : base;
            rr[q] = ei[idx];
            cc[q] = ei[NE + idx];
            if (v) atomicAdd(&lh[cc[q]>>7], 1);
        }
        __syncthreads();
        for (int b=t; b<NB; b+=1024){
            int n = lh[b];
            lb[b] = n ? atomicAdd(&bcursor[b], n) : 0;
            lh[b] = 0;
        }
        __syncthreads();
        #pragma unroll
        for (int q=0;q<4;q++){
            int i = t + q*1024;
            if (i < SC_CHUNK){
                int b = cc[q] >> 7;
                int rk = atomicAdd(&lh[b], 1);
                ebuf[lb[b] + rk] = (rr[q] << 7) | (cc[q] & 127);
            }
        }
        __syncthreads();
    }
    grid.sync();

    // ---- stage 2: per-bucket counting sort (782 buckets over blocks) ----
    for (int b = blockIdx.x; b < NB; b += gridDim.x){
        int e0 = b * BCAP;
        int nE = bcursor[b] - e0;
        if (t < 128) lh[t] = 0;
        __syncthreads();
        for (int i=t; i<nE; i+=1024) atomicAdd(&lh[ebuf[e0+i] & 127], 1);
        __syncthreads();
        int c = (t < 128) ? lh[t] : 0;
        if (t < 128) s_s[t] = c;
        __syncthreads();
        #pragma unroll
        for (int off=1; off<128; off<<=1){
            int v = (t >= off && t < 128) ? s_s[t-off] : 0;
            __syncthreads();
            if (t < 128) s_s[t] += v;
            __syncthreads();
        }
        int node = b*128 + t;
        if (t < 128){
            int excl = s_s[t] - c;
            s_lcur[t] = excl;
            if (node < NN){
                nstart[node] = e0 + excl;
                cnt[node] = c;
                dinv[node] = rsqrtf((float)c + 2.0f);
            }
        }
        __syncthreads();
        for (int i=t; i<nE; i+=1024){
            int v = ebuf[e0 + i];
            int nl = v & 127;
            int rk = atomicAdd(&s_lcur[nl], 1);
            sorted[rk] = (v >> 7) << 5;   // row * 32 (uint-word offset into xws8)
        }
        __syncthreads();
        for (int i=t; i<nE; i+=1024) ebuf2[e0 + i] = sorted[i];
        __syncthreads();
    }
}

// ---------------- xws = (x @ W_gcn) * dinv[row], bf16 MFMA, stored fp8 e4m3 ----------------
__global__ __launch_bounds__(256) void k_xws(const float* __restrict__ x, const float* __restrict__ W,
                                             const float* __restrict__ dinv, unsigned char* __restrict__ xws8){
    __shared__ short Xs[128*72];   // [row][k], stride 72 (K=64)
    __shared__ short Ws[128*72];   // [feature][k], stride 72
    int t = threadIdx.x;
    int rowBase = blockIdx.x * 128;
    #pragma unroll
    for (int i=0;i<32;i++){
        int id = i*256+t; int k = id>>7, n = id&127;
        Ws[n*72 + k] = f2bs(W[id]);
    }
    #pragma unroll
    for (int i=0;i<8;i++){
        int id = i*256+t;              // 2048 float4 slots
        int r = id>>4; int k4 = (id&15)*4;
        int row = rowBase + r; if (row >= NN) row = NN-1;
        float4 v = *(const float4*)&x[(size_t)row*INF + k4];
        *(unsigned int*)&Xs[r*72 + k4]     = pk2(v.x, v.y);
        *(unsigned int*)&Xs[r*72 + k4 + 2] = pk2(v.z, v.w);
    }
    __syncthreads();
    int lane = t & 63, w = t >> 6;
    int lr = lane & 15, quad = lane >> 4;
    f32x4 acc[2][8];
    #pragma unroll
    for (int i=0;i<2;i++)
        #pragma unroll
        for (int j=0;j<8;j++) acc[i][j] = (f32x4){0.f,0.f,0.f,0.f};
    #pragma unroll
    for (int ks=0; ks<2; ++ks){
        int kb = ks*32 + quad*8;
        short8 b0 = *(const short8*)&Xs[((w  )*16 + lr)*72 + kb];
        short8 b1 = *(const short8*)&Xs[((w+4)*16 + lr)*72 + kb];
        #pragma unroll
        for (int mt=0; mt<8; ++mt){
            short8 a = *(const short8*)&Ws[(mt*16 + lr)*72 + kb];
            acc[0][mt] = __builtin_amdgcn_mfma_f32_16x16x32_bf16(a, b0, acc[0][mt], 0, 0, 0);
            acc[1][mt] = __builtin_amdgcn_mfma_f32_16x16x32_bf16(a, b1, acc[1][mt], 0, 0, 0);
        }
    }
    #pragma unroll
    for (int rt=0; rt<2; ++rt){
        int row = rowBase + (w + rt*4)*16 + lr;
        if (row < NN){
            float dv = dinv[row];
            #pragma unroll
            for (int mt=0; mt<8; ++mt){
                int p = __builtin_amdgcn_cvt_pk_fp8_f32(acc[rt][mt][0]*dv, acc[rt][mt][1]*dv, 0, false);
                p     = __builtin_amdgcn_cvt_pk_fp8_f32(acc[rt][mt][2]*dv, acc[rt][mt][3]*dv, p, true);
                *(int*)&xws8[(size_t)row*F + mt*16 + quad*4] = p;
            }
        }
    }
}

// ---------------- fused: CSR gather + GCN epilogue + BN + ReLU -> h,hb + pool -> z, znb ----------------
__global__ __launch_bounds__(256) void k_aggpool(const unsigned char* __restrict__ xws8,
                                                 const int* __restrict__ nstart, const int* __restrict__ cnt,
                                                 const float* __restrict__ dinv, const float* __restrict__ b_gcn,
                                                 const float* __restrict__ bn_g, const float* __restrict__ bn_b,
                                                 const int* __restrict__ ebuf2,
                                                 const float* __restrict__ lnpre_g, const float* __restrict__ lnpre_b,
                                                 float* __restrict__ h, unsigned short* __restrict__ hb,
                                                 float* __restrict__ z, unsigned short* __restrict__ znb){
    __shared__ float zacc[4][128];
    int t = threadIdx.x;
    int lane = t & 63, w = t >> 6;
    int half = lane >> 5, lh = lane & 31;
    int g = blockIdx.x;
    const unsigned int* xw32 = (const unsigned int*)xws8;   // row stride = 32 uints
    unsigned int* hb32 = (unsigned int*)hb;
    unsigned int* znb32 = (unsigned int*)znb;

    float4 bg4  = *(const float4*)&b_gcn[4*lh];
    float4 bng4 = *(const float4*)&bn_g[4*lh];
    float4 bnb4 = *(const float4*)&bn_b[4*lh];
    const float bns = rsqrtf(1.f + 1e-5f);

    float za0=0.f, za1=0.f, za2=0.f, za3=0.f;

    for (int i = w; i < 50; i += 4){
        int node = g*50 + i;
        int s0n = nstart[node]; int dg = cnt[node]; float dv = dinv[node];
        unsigned int us = xw32[node*32 + lh];   // self-loop, issued early
        float a0=0.f, a1=0.f, a2=0.f, a3=0.f;
        int j=0;
        for (; j+8<=dg; j+=8){
            int r0 = ebuf2[s0n+j+0+half];
            int r1 = ebuf2[s0n+j+2+half];
            int r2 = ebuf2[s0n+j+4+half];
            int r3 = ebuf2[s0n+j+6+half];
            unsigned int u0 = xw32[r0 + lh];
            unsigned int u1 = xw32[r1 + lh];
            unsigned int u2 = xw32[r2 + lh];
            unsigned int u3 = xw32[r3 + lh];
            f32x2 l0 = __builtin_amdgcn_cvt_pk_f32_fp8(u0, false);
            f32x2 h0 = __builtin_amdgcn_cvt_pk_f32_fp8(u0, true);
            f32x2 l1 = __builtin_amdgcn_cvt_pk_f32_fp8(u1, false);
            f32x2 h1 = __builtin_amdgcn_cvt_pk_f32_fp8(u1, true);
            f32x2 l2 = __builtin_amdgcn_cvt_pk_f32_fp8(u2, false);
            f32x2 h2 = __builtin_amdgcn_cvt_pk_f32_fp8(u2, true);
            f32x2 l3 = __builtin_amdgcn_cvt_pk_f32_fp8(u3, false);
            f32x2 h3 = __builtin_amdgcn_cvt_pk_f32_fp8(u3, true);
            a0 += (l0.x + l1.x) + (l2.x + l3.x);
            a1 += (l0.y + l1.y) + (l2.y + l3.y);
            a2 += (h0.x + h1.x) + (h2.x + h3.x);
            a3 += (h0.y + h1.y) + (h2.y + h3.y);
        }
        for (; j+2<=dg; j+=2){
            int r0 = ebuf2[s0n+j+half];
            unsigned int u0 = xw32[r0 + lh];
            f32x2 l0 = __builtin_amdgcn_cvt_pk_f32_fp8(u0, false);
            f32x2 h0 = __builtin_amdgcn_cvt_pk_f32_fp8(u0, true);
            a0 += l0.x; a1 += l0.y; a2 += h0.x; a3 += h0.y;
        }
        if (j < dg && half == 0){
            int r0 = ebuf2[s0n+j];
            unsigned int u0 = xw32[r0 + lh];
            f32x2 l0 = __builtin_amdgcn_cvt_pk_f32_fp8(u0, false);
            f32x2 h0 = __builtin_amdgcn_cvt_pk_f32_fp8(u0, true);
            a0 += l0.x; a1 += l0.y; a2 += h0.x; a3 += h0.y;
        }
        a0 += __shfl_xor(a0, 32);
        a1 += __shfl_xor(a1, 32);
        a2 += __shfl_xor(a2, 32);
        a3 += __shfl_xor(a3, 32);
        f32x2 fl = __builtin_amdgcn_cvt_pk_f32_fp8(us, false);
        f32x2 fh = __builtin_amdgcn_cvt_pk_f32_fp8(us, true);
        float p0 = dv*(a0 + 2.f*fl.x) + bg4.x;
        float p1 = dv*(a1 + 2.f*fl.y) + bg4.y;
        float p2 = dv*(a2 + 2.f*fh.x) + bg4.z;
        float p3 = dv*(a3 + 2.f*fh.y) + bg4.w;
        p0 = fmaxf(p0*bns*bng4.x + bnb4.x, 0.f);
        p1 = fmaxf(p1*bns*bng4.y + bnb4.y, 0.f);
        p2 = fmaxf(p2*bns*bng4.z + bnb4.z, 0.f);
        p3 = fmaxf(p3*bns*bng4.w + bnb4.w, 0.f);
        if (half == 0){
            *(float4*)&h[(size_t)node*F + 4*lh] = make_float4(p0,p1,p2,p3);
            *(uint2*)&hb32[(size_t)node*64 + 2*lh] = make_uint2(pk2(p0,p1), pk2(p2,p3));
        }
        za0 += p0; za1 += p1; za2 += p2; za3 += p3;
    }
    if (half == 0)
        *(float4*)&zacc[w][4*lh] = make_float4(za0, za1, za2, za3);
    __syncthreads();
    if (w == 0){
        float4 v0 = *(const float4*)&zacc[0][4*lh];
        float4 v1 = *(const float4*)&zacc[1][4*lh];
        float4 v2 = *(const float4*)&zacc[2][4*lh];
        float4 v3 = *(const float4*)&zacc[3][4*lh];
        float s0 = ((v0.x+v1.x)+(v2.x+v3.x)) / 50.0f;
        float s1 = ((v0.y+v1.y)+(v2.y+v3.y)) / 50.0f;
        float s2 = ((v0.z+v1.z)+(v2.z+v3.z)) / 50.0f;
        float s3 = ((v0.w+v1.w)+(v2.w+v3.w)) / 50.0f;
        if (half == 0)
            *(float4*)&z[(size_t)g*F + 4*lh] = make_float4(s0,s1,s2,s3);
        float s = (s0+s1)+(s2+s3);
        #pragma unroll
        for (int off=1; off<32; off<<=1) s += __shfl_xor(s, off);
        float m = s * (1.f/128.f);
        float d0=s0-m, d1=s1-m, d2=s2-m, d3=s3-m;
        float vv = (d0*d0+d1*d1)+(d2*d2+d3*d3);
        #pragma unroll
        for (int off=1; off<32; off<<=1) vv += __shfl_xor(vv, off);
        float rs = rsqrtf(vv*(1.f/128.f) + 1e-5f);
        float4 lg = *(const float4*)&lnpre_g[4*lh];
        float4 lb = *(const float4*)&lnpre_b[4*lh];
        if (half == 0){
            float o0 = d0*rs*lg.x+lb.x, o1 = d1*rs*lg.y+lb.y;
            float o2 = d2*rs*lg.z+lb.z, o3 = d3*rs*lg.w+lb.w;
            *(uint2*)&znb32[(size_t)g*64 + 2*lh] = make_uint2(pk2(o0,o1), pk2(o2,o3));
        }
    }
}

// ================= cooperative chain: qkv -> attn -> wo_ln -> ffn1 -> ffn2 -> ln_red_gsi =================
// Stage bodies verbatim from the proven round-10 kernels; units strided over a fixed grid;
// single 29.2KB LDS union (attn is the max user). 1 block/CU co-residency trivially satisfied.
__global__ __launch_bounds__(256) void k_chain(const unsigned short* __restrict__ znb,
                                               const float* __restrict__ z,
                                               const unsigned short* __restrict__ Wqb,
                                               const unsigned short* __restrict__ Wkb,
                                               const unsigned short* __restrict__ Wvb,
                                               const float* __restrict__ bq, const float* __restrict__ bk,
                                               const float* __restrict__ bv,
                                               float* __restrict__ qb, float* __restrict__ kb2,
                                               float* __restrict__ vb, float* __restrict__ ao,
                                               const float* __restrict__ Wo, const float* __restrict__ bo,
                                               const float* __restrict__ ln1_g, const float* __restrict__ ln1_b,
                                               float* __restrict__ zd1, unsigned short* __restrict__ zd1b,
                                               const unsigned short* __restrict__ W1b, const float* __restrict__ b1,
                                               unsigned short* __restrict__ ffn1b,
                                               const unsigned short* __restrict__ W2b, float* __restrict__ part,
                                               const float* __restrict__ b2, const float* __restrict__ ln2_g,
                                               const float* __restrict__ ln2_b, const float* __restrict__ Wgbot,
                                               const float* __restrict__ bg, float* __restrict__ zd2,
                                               float* __restrict__ gsi){
    cg::grid_group grid = cg::this_grid();
    __shared__ __align__(16) char cs[29248];
    int t = threadIdx.x;
    int lane = t & 63, w = t >> 6;
    int lr = lane & 15, quad = lane >> 4;
    unsigned int* zd1b32 = (unsigned int*)zd1b;

    // ---- stage 1: QKV (96 units = 3 weights x 32 row-tiles) ----
    for (int u = blockIdx.x; u < 96; u += gridDim.x){
        int zsel = u >> 5, rt = u & 31;
        const unsigned short* B = (zsel==0)?Wqb:(zsel==1)?Wkb:Wvb;
        const float* bias = (zsel==0)?bq:(zsel==1)?bk:bv;
        float* C = (zsel==0)?qb:(zsel==1)?kb2:vb;
        int mrow0 = rt*64 + w*16;
        f32x4 acc[8];
        #pragma unroll
        for (int j=0;j<8;j++) acc[j] = (f32x4){0.f,0.f,0.f,0.f};
        #pragma unroll
        for (int ks=0; ks<4; ++ks){
            int kb = ks*32 + quad*8;
            int row = mrow0 + lr;
            if (row >= NG) row = NG-1;
            short8 a = *(const short8*)&znb[(size_t)row*F + kb];
            #pragma unroll
            for (int nt=0; nt<8; ++nt){
                short8 b = *(const short8*)&B[(size_t)(nt*16 + lr)*128 + kb];
                acc[nt] = __builtin_amdgcn_mfma_f32_16x16x32_bf16(a, b, acc[nt], 0, 0, 0);
            }
        }
        #pragma unroll
        for (int r=0; r<4; ++r){
            int row = mrow0 + quad*4 + r;
            if (row >= NG) continue;
            #pragma unroll
            for (int nt=0; nt<8; ++nt){
                int col = nt*16 + lr;
                C[(size_t)row*F + col] = acc[nt][r] + bias[col];
            }
        }
    }
    grid.sync();

    // ---- stage 2: attention (160 units = 40 sets x 4 heads) ----
    for (int u = blockIdx.x; u < NS*4; u += gridDim.x){
        float* Qs = (float*)cs;
        float* Ks = (float*)(cs + 6400);
        float* Vs = (float*)(cs + 12800);
        float* Sc = (float*)(cs + 19200);
        int s = u >> 2; int hh = u & 3;
        for (int idx=t; idx<1600; idx+=256){
            int i = idx>>5, d = idx&31;
            size_t gi = (size_t)(s*50+i)*F + hh*32 + d;
            Qs[idx]=qb[gi]; Ks[idx]=kb2[gi]; Vs[idx]=vb[gi];
        }
        __syncthreads();
        for (int idx=t; idx<2500; idx+=256){
            int qi = idx/50, ki = idx%50;
            float acc=0.f;
            #pragma unroll 8
            for (int d=0;d<32;d++) acc += Qs[qi*32+d]*Ks[ki*32+d];
            Sc[idx] = acc * 0.17677669529663687f;   // 1/sqrt(32)
        }
        __syncthreads();
        if (t < 50){
            float m=-1e30f;
            for (int j=0;j<50;j++) m = fmaxf(m, Sc[t*50+j]);
            float sum=0.f;
            for (int j=0;j<50;j++){ float e=__expf(Sc[t*50+j]-m); Sc[t*50+j]=e; sum+=e; }
            float inv = 1.f/sum;
            for (int j=0;j<50;j++) Sc[t*50+j] *= inv;
        }
        __syncthreads();
        for (int idx=t; idx<1600; idx+=256){
            int qi = idx>>5, d = idx&31;
            float acc=0.f;
            #pragma unroll 10
            for (int ki=0;ki<50;ki++) acc += Sc[qi*50+ki]*Vs[ki*32+d];
            ao[(size_t)(s*50+qi)*F + hh*32 + d] = acc;
        }
        __syncthreads();
    }
    grid.sync();

    // ---- stage 3: wo_ln (63 units of 32 rows) ----
    for (int u = blockIdx.x; u < 63; u += gridDim.x){
        float* As = (float*)cs;              // 32*36 floats
        float* Bs = (float*)(cs + 4608);     // 32*128 floats
        int rowBase = u*32;
        int c0 = (t&31)*4, r0 = (t>>5)*4;
        float acc[4][4];
        #pragma unroll
        for (int i=0;i<4;i++){ acc[i][0]=0.f; acc[i][1]=0.f; acc[i][2]=0.f; acc[i][3]=0.f; }
        for (int kb=0; kb<F; kb+=32){
            #pragma unroll
            for (int i=0;i<4;i++){
                int id = i*256+t; int kk = id&31; int r = id>>5;
                int row = rowBase + r;
                As[kk*36+r] = (row<NG) ? ao[(size_t)row*F + kb + kk] : 0.f;
            }
            #pragma unroll
            for (int i=0;i<16;i++){
                int id = i*256+t; int c = id&127; int kk = id>>7;
                Bs[kk*128+c] = Wo[(size_t)(kb+kk)*F + c];
            }
            __syncthreads();
            for (int kk=0;kk<32;kk++){
                float4 a = *(const float4*)&As[kk*36+r0];
                float4 bv4 = *(const float4*)&Bs[kk*128+c0];
                float av[4]={a.x,a.y,a.z,a.w}; float bb[4]={bv4.x,bv4.y,bv4.z,bv4.w};
                #pragma unroll
                for(int i=0;i<4;i++)
                    #pragma unroll
                    for(int j=0;j<4;j++) acc[i][j] += av[i]*bb[j];
            }
            __syncthreads();
        }
        float4 bo4 = *(const float4*)&bo[c0];
        float4 g4  = *(const float4*)&ln1_g[c0];
        float4 b4  = *(const float4*)&ln1_b[c0];
        #pragma unroll
        for (int i=0;i<4;i++){
            int row = rowBase + r0 + i;
            float v0=0.f,v1=0.f,v2=0.f,v3=0.f;
            if (row < NG){
                float4 zr = *(const float4*)&z[(size_t)row*F + c0];
                v0 = acc[i][0] + bo4.x + zr.x;
                v1 = acc[i][1] + bo4.y + zr.y;
                v2 = acc[i][2] + bo4.z + zr.z;
                v3 = acc[i][3] + bo4.w + zr.w;
            }
            float s = (v0+v1)+(v2+v3);
            #pragma unroll
            for (int off=1; off<32; off<<=1) s += __shfl_xor(s, off);
            float m = s * (1.f/128.f);
            float d0=v0-m, d1=v1-m, d2=v2-m, d3=v3-m;
            float vv = (d0*d0+d1*d1)+(d2*d2+d3*d3);
            #pragma unroll
            for (int off=1; off<32; off<<=1) vv += __shfl_xor(vv, off);
            float rs = rsqrtf(vv*(1.f/128.f) + 1e-5f);
            if (row < NG){
                float o0 = d0*rs*g4.x+b4.x, o1 = d1*rs*g4.y+b4.y;
                float o2 = d2*rs*g4.z+b4.z, o3 = d3*rs*g4.w+b4.w;
                *(float4*)&zd1[(size_t)row*F + c0] = make_float4(o0,o1,o2,o3);
                *(uint2*)&zd1b32[(size_t)row*(F/2) + c0/2] = make_uint2(pk2(o0,o1), pk2(o2,o3));
            }
        }
        __syncthreads();
    }
    grid.sync();

    // ---- stage 4: ffn1 (256 units = 32 row-tiles x 8 col-tiles) ----
    for (int u = blockIdx.x; u < 256; u += gridDim.x){
        int rt = u & 31, ct = u >> 5;
        int mrow0 = rt*64 + w*16;
        int colBase = ct*128;
        f32x4 acc[8];
        #pragma unroll
        for (int j=0;j<8;j++) acc[j] = (f32x4){0.f,0.f,0.f,0.f};
        #pragma unroll
        for (int ks=0; ks<4; ++ks){
            int kb = ks*32 + quad*8;
            int row = mrow0 + lr;
            if (row >= NG) row = NG-1;
            short8 a = *(const short8*)&zd1b[(size_t)row*F + kb];
            #pragma unroll
            for (int nt=0; nt<8; ++nt){
                short8 b = *(const short8*)&W1b[(size_t)(colBase + nt*16 + lr)*128 + kb];
                acc[nt] = __builtin_amdgcn_mfma_f32_16x16x32_bf16(a, b, acc[nt], 0, 0, 0);
            }
        }
        #pragma unroll
        for (int r=0; r<4; ++r){
            int row = mrow0 + quad*4 + r;
            if (row >= NG) continue;
            #pragma unroll
            for (int nt=0; nt<8; ++nt){
                int col = colBase + nt*16 + lr;
                ffn1b[(size_t)row*FFN_DIM + col] = (unsigned short)f2bs(fmaxf(acc[nt][r] + b1[col], 0.f));
            }
        }
    }
    grid.sync();

    // ---- stage 5: ffn2 split-K (256 units = 32 row-tiles x 8 k-chunks) ----
    for (int u = blockIdx.x; u < 256; u += gridDim.x){
        int rt = u & 31, kc = u >> 5;
        int mrow0 = rt*64 + w*16;
        int kbeg = kc*128;
        f32x4 acc[8];
        #pragma unroll
        for (int j=0;j<8;j++) acc[j] = (f32x4){0.f,0.f,0.f,0.f};
        #pragma unroll
        for (int ks=0; ks<4; ++ks){
            int kb = ks*32 + quad*8;
            int row = mrow0 + lr;
            if (row >= NG) row = NG-1;
            short8 a = *(const short8*)&ffn1b[(size_t)row*FFN_DIM + kbeg + kb];
            #pragma unroll
            for (int nt=0; nt<8; ++nt){
                short8 b = *(const short8*)&W2b[(size_t)(nt*16 + lr)*1024 + kbeg + kb];
                acc[nt] = __builtin_amdgcn_mfma_f32_16x16x32_bf16(a, b, acc[nt], 0, 0, 0);
            }
        }
        float* Cp = part + (size_t)kc*NG*F;
        #pragma unroll
        for (int r=0; r<4; ++r){
            int row = mrow0 + quad*4 + r;
            if (row >= NG) continue;
            #pragma unroll
            for (int nt=0; nt<8; ++nt){
                int col = nt*16 + lr;
                Cp[(size_t)row*F + col] = acc[nt][r];
            }
        }
    }
    grid.sync();

    // ---- stage 6: ln_red_gsi (500 units of 4 rows) ----
    for (int u = blockIdx.x; u < NG/4; u += gridDim.x){
        float* Zs = (float*)cs;              // [4][128]
        float* Bs = (float*)(cs + 2048);     // 32*128 floats
        int rquad = t>>6;
        int row = u*4 + rquad;
        int i0 = row*F + 2*lane;
        float x0 = zd1[i0] + b2[2*lane], x1 = zd1[i0+1] + b2[2*lane+1];
        #pragma unroll
        for (int zz=0; zz<KSPLIT; ++zz){
            x0 += part[(size_t)zz*NG*F + i0];
            x1 += part[(size_t)zz*NG*F + i0 + 1];
        }
        float s = x0+x1;
        for (int off=1; off<64; off<<=1) s += __shfl_xor(s, off);
        float m = s * (1.f/128.f);
        float d0 = x0-m, d1 = x1-m;
        float vv = d0*d0 + d1*d1;
        for (int off=1; off<64; off<<=1) vv += __shfl_xor(vv, off);
        float rs = rsqrtf(vv*(1.f/128.f) + 1e-5f);
        float o0 = d0*rs*ln2_g[2*lane]   + ln2_b[2*lane];
        float o1 = d1*rs*ln2_g[2*lane+1] + ln2_b[2*lane+1];
        zd2[i0]   = o0;
        zd2[i0+1] = o1;
        Zs[rquad*128 + 2*lane]   = o0;
        Zs[rquad*128 + 2*lane+1] = o1;
        __syncthreads();
        int col = t & 127, rp = t >> 7;
        float a0=0.f, a1=0.f;
        for (int kb=0; kb<F; kb+=32){
            #pragma unroll
            for (int i=0;i<16;i++){
                int id = i*256+t; int c = id&127; int kk = id>>7;
                Bs[kk*128+c] = Wgbot[(size_t)(kb+kk)*F + c];
            }
            __syncthreads();
            for (int kk=0;kk<32;kk++){
                float wv = Bs[kk*128+col];
                a0 += Zs[rp*128 + kb+kk]     * wv;
                a1 += Zs[(rp+2)*128 + kb+kk] * wv;
            }
            __syncthreads();
        }
        float bgc = bg[col];
        gsi[(size_t)(u*4 + rp)*F + col]     = a0 + bgc;
        gsi[(size_t)(u*4 + rp + 2)*F + col] = a1 + bgc;
        __syncthreads();
    }
}

// ---------------- MFMA gate: 64-row tiles, B from global bf16 Wgb (no LDS, no barriers) ----------------
__global__ __launch_bounds__(256) void k_gate_mfma(const float* __restrict__ h,
                                                   const unsigned short* __restrict__ hb,
                                                   const unsigned short* __restrict__ Wgb,
                                                   const float* __restrict__ gsi, const float* __restrict__ zd2,
                                                   float* __restrict__ out){
    int t = threadIdx.x;
    int lane = t & 63, w = t >> 6;
    int lr = lane & 15, quad = lane >> 4;
    int mrow0 = blockIdx.x*64 + w*16;
    f32x4 acc[8];
    #pragma unroll
    for (int j=0;j<8;j++) acc[j] = (f32x4){0.f,0.f,0.f,0.f};
    #pragma unroll
    for (int ks=0; ks<4; ++ks){
        int kb = ks*32 + quad*8;
        int row = mrow0 + lr;
        if (row >= NN) row = NN-1;
        short8 a = *(const short8*)&hb[(size_t)row*F + kb];
        #pragma unroll
        for (int nt=0; nt<8; ++nt){
            short8 b = *(const short8*)&Wgb[(size_t)(nt*16 + lr)*128 + kb];
            acc[nt] = __builtin_amdgcn_mfma_f32_16x16x32_bf16(a, b, acc[nt], 0, 0, 0);
        }
    }
    #pragma unroll
    for (int r=0; r<4; ++r){
        int row = mrow0 + quad*4 + r;
        if (row >= NN) continue;
        int g = row / 50;
        const float* gs = &gsi[(size_t)g*F];
        const float* zs = &zd2[(size_t)g*F];
        const float* hr = &h[(size_t)row*F];
        float* orow = &out[(size_t)row*F];
        #pragma unroll
        for (int nt=0; nt<8; ++nt){
            int col = nt*16 + lr;
            float L = acc[nt][r] + gs[col];
            float gate = 1.f/(1.f + __expf(-L));
            orow[col] = gate*zs[col] + (1.f-gate)*hr[col];
        }
    }
}

extern "C" void kernel_launch(void* const* d_in, const int* in_sizes, int n_in,
                              void* d_out, int out_size, void* d_ws, size_t ws_size,
                              hipStream_t stream) {
    const float* x      = (const float*)d_in[0];
    const int*   ei     = (const int*)d_in[1];
    const float* W_gcn  = (const float*)d_in[4];
    const float* b_gcn  = (const float*)d_in[5];
    const float* bn_g   = (const float*)d_in[6];
    const float* bn_b   = (const float*)d_in[7];
    const float* lnpre_g= (const float*)d_in[8];
    const float* lnpre_b= (const float*)d_in[9];
    const float* Wq     = (const float*)d_in[10];
    const float* bq     = (const float*)d_in[11];
    const float* Wk     = (const float*)d_in[12];
    const float* bk     = (const float*)d_in[13];
    const float* Wv     = (const float*)d_in[14];
    const float* bv     = (const float*)d_in[15];
    const float* Wo     = (const float*)d_in[16];
    const float* bo     = (const float*)d_in[17];
    const float* ln1_g  = (const float*)d_in[18];
    const float* ln1_b  = (const float*)d_in[19];
    const float* W1     = (const float*)d_in[20];
    const float* b1     = (const float*)d_in[21];
    const float* W2     = (const float*)d_in[22];
    const float* b2     = (const float*)d_in[23];
    const float* ln2_g  = (const float*)d_in[24];
    const float* ln2_b  = (const float*)d_in[25];
    const float* Wg     = (const float*)d_in[26];
    const float* bg     = (const float*)d_in[27];
    float* out = (float*)d_out;
    char* ws = (char*)d_ws;

    // workspace layout
    size_t o = 0;
    unsigned char* xws8 = (unsigned char*)(ws + o); o += (size_t)NN*F; // 12.8 MB (fp8)
    float* h     = (float*)(ws + o); o += (size_t)NN*F*4;            // 51.2 MB
    unsigned short* hb = (unsigned short*)(ws + o); o += (size_t)NN*F*2; // 25.6 MB (bf16)
    int*   cnt   = (int*)(ws + o);   o += (size_t)NN*4;
    int*   nstart= (int*)(ws + o);   o += (size_t)NN*4;
    int*   ebuf  = (int*)(ws + o);   o += (size_t)NB*BCAP*4;         // 9.6 MB
    int*   ebuf2 = (int*)(ws + o);   o += (size_t)NB*BCAP*4;         // 9.6 MB
    float* dinv  = (float*)(ws + o); o += (size_t)NN*4;
    int*   bcursor=(int*)(ws + o);   o += 1024*4;
    unsigned short* Wgb = (unsigned short*)(ws + o); o += 16384*2;
    unsigned short* Wqb = (unsigned short*)(ws + o); o += 16384*2;
    unsigned short* Wkb = (unsigned short*)(ws + o); o += 16384*2;
    unsigned short* Wvb = (unsigned short*)(ws + o); o += 16384*2;
    unsigned short* W1b = (unsigned short*)(ws + o); o += (size_t)131072*2;  // 256 KB
    unsigned short* W2b = (unsigned short*)(ws + o); o += (size_t)131072*2;  // 256 KB
    float* z     = (float*)(ws + o); o += (size_t)NG*F*4;
    unsigned short* znb = (unsigned short*)(ws + o); o += (size_t)NG*F*2;
    float* qb    = (float*)(ws + o); o += (size_t)NG*F*4;
    float* kb2   = (float*)(ws + o); o += (size_t)NG*F*4;
    float* vb    = (float*)(ws + o); o += (size_t)NG*F*4;
    float* ao    = (float*)(ws + o); o += (size_t)NG*F*4;
    float* zd1   = (float*)(ws + o); o += (size_t)NG*F*4;
    unsigned short* zd1b = (unsigned short*)(ws + o); o += (size_t)NG*F*2;
    unsigned short* ffn1b = (unsigned short*)(ws + o); o += (size_t)NG*FFN_DIM*2; // 4.1 MB
    float* part  = (float*)(ws + o); o += (size_t)KSPLIT*NG*F*4;     // 8.2 MB
    float* zd2   = (float*)(ws + o); o += (size_t)NG*F*4;
    float* gsi   = (float*)(ws + o); o += (size_t)NG*F*4;
    const float* Wgbot = Wg + (size_t)F*F;

    // ---- front (cooperative): init + scatter + sort ----
    {
        void* fargs[] = { (void*)&bcursor, (void*)&ei, (void*)&ebuf, (void*)&cnt, (void*)&dinv,
                          (void*)&nstart, (void*)&ebuf2,
                          (void*)&Wq, (void*)&Wk, (void*)&Wv, (void*)&W1, (void*)&W2, (void*)&Wg,
                          (void*)&Wqb, (void*)&Wkb, (void*)&Wvb, (void*)&W1b, (void*)&W2b, (void*)&Wgb };
        hipLaunchCooperativeKernel((const void*)k_front, dim3(256), dim3(1024), fargs, 0, stream);
    }
    k_xws<<<(NN+127)/128, 256, 0, stream>>>(x, W_gcn, dinv, xws8);
    k_aggpool<<<NG, 256, 0, stream>>>(xws8, nstart, cnt, dinv, b_gcn, bn_g, bn_b, ebuf2,
                                      lnpre_g, lnpre_b, h, hb, z, znb);

    // ---- set transformer (cooperative, one dispatch) ----
    {
        void* cargs[] = { (void*)&znb, (void*)&z, (void*)&Wqb, (void*)&Wkb, (void*)&Wvb,
                          (void*)&bq, (void*)&bk, (void*)&bv,
                          (void*)&qb, (void*)&kb2, (void*)&vb, (void*)&ao,
                          (void*)&Wo, (void*)&bo, (void*)&ln1_g, (void*)&ln1_b,
                          (void*)&zd1, (void*)&zd1b, (void*)&W1b, (void*)&b1, (void*)&ffn1b,
                          (void*)&W2b, (void*)&part, (void*)&b2, (void*)&ln2_g, (void*)&ln2_b,
                          (void*)&Wgbot, (void*)&bg, (void*)&zd2, (void*)&gsi };
        hipLaunchCooperativeKernel((const void*)k_chain, dim3(256), dim3(256), cargs, 0, stream);
    }

    // ---- gated fusion -> output ----
    k_gate_mfma<<<(NN+63)/64, 256, 0, stream>>>(h, hb, Wgb, gsi, zd2, out);
}

// Round 12
// 373.394 us; speedup vs baseline: 1.5524x; 1.5524x over previous
//
#include <hip/hip_runtime.h>
#include <hip/hip_bf16.h>
#include <cstddef>

#define NN 100000
#define NE 1600000
#define NG 2000
#define NS 40
#define INF 64
#define F 128
#define FFN_DIM 1024
#define NB 782            // ceil(100000/128) buckets of 128 nodes
#define BCAP 3072         // fixed bucket capacity (mean 2048, sigma 45 -> 19+ sigma margin)
#define SC_BLOCKS 512
#define SC_CHUNK 3125     // 512*3125 = 1.6M edges exactly
#define NXB 782           // xws row-tiles
#define NWB 72            // weight-conversion blocks appended to k_xws grid

using bf16 = __hip_bfloat16;
typedef __attribute__((ext_vector_type(8))) short short8;
typedef __attribute__((ext_vector_type(4))) float f32x4;
typedef __attribute__((ext_vector_type(2))) float f32x2;

__device__ __forceinline__ short f2bs(float f){
    union { bf16 b; short s; } u; u.b = __float2bfloat16(f); return u.s;
}
__device__ __forceinline__ unsigned int pk2(float a, float b){
    return (unsigned int)(unsigned short)f2bs(a) | ((unsigned int)(unsigned short)f2bs(b) << 16);
}

// ---------------- xws = (x @ W_gcn) * dinv[row] -> fp8, PLUS weight-table conversion ----------------
// Blocks [0,NXB): xws MFMA tiles. Blocks [NXB, NXB+NWB): convert all set-transformer
// weights to transposed bf16 [n][k] tables (consumed by k_settf2 / k_gate_mfma).
__global__ __launch_bounds__(256) void k_xws(const float* __restrict__ x, const float* __restrict__ W,
                                             const float* __restrict__ dinv, unsigned char* __restrict__ xws8,
                                             const float* __restrict__ Wq, const float* __restrict__ Wk,
                                             const float* __restrict__ Wv, const float* __restrict__ Wo,
                                             const float* __restrict__ W1, const float* __restrict__ W2,
                                             const float* __restrict__ Wg,
                                             unsigned short* __restrict__ Wqb, unsigned short* __restrict__ Wkb,
                                             unsigned short* __restrict__ Wvb, unsigned short* __restrict__ Wob,
                                             unsigned short* __restrict__ W1b, unsigned short* __restrict__ W2b,
                                             unsigned short* __restrict__ Wgb, unsigned short* __restrict__ Wgbotb){
    int t = threadIdx.x;
    if (blockIdx.x >= NXB){
        int wt = (blockIdx.x - NXB)*256 + t;
        const int ws = NWB*256;
        for (int i=wt; i<16384; i+=ws){
            int k = i>>7, n = i&127;
            Wqb[n*128+k]    = (unsigned short)f2bs(Wq[(size_t)k*F+n]);
            Wkb[n*128+k]    = (unsigned short)f2bs(Wk[(size_t)k*F+n]);
            Wvb[n*128+k]    = (unsigned short)f2bs(Wv[(size_t)k*F+n]);
            Wob[n*128+k]    = (unsigned short)f2bs(Wo[(size_t)k*F+n]);
            Wgb[n*128+k]    = (unsigned short)f2bs(Wg[(size_t)k*F+n]);
            Wgbotb[n*128+k] = (unsigned short)f2bs(Wg[(size_t)(F+k)*F+n]);
        }
        for (int i=wt; i<131072; i+=ws){
            int k = i>>10, n = i&1023;
            W1b[(size_t)n*128+k] = (unsigned short)f2bs(W1[(size_t)k*FFN_DIM+n]);
        }
        for (int i=wt; i<131072; i+=ws){
            int n = i>>10, k = i&1023;
            W2b[(size_t)n*1024+k] = (unsigned short)f2bs(W2[(size_t)k*F+n]);
        }
        return;
    }
    __shared__ short Xs[128*72];   // [row][k], stride 72 (K=64)
    __shared__ short Ws[128*72];   // [feature][k], stride 72
    int rowBase = blockIdx.x * 128;
    #pragma unroll
    for (int i=0;i<32;i++){
        int id = i*256+t; int k = id>>7, n = id&127;
        Ws[n*72 + k] = f2bs(W[id]);
    }
    #pragma unroll
    for (int i=0;i<8;i++){
        int id = i*256+t;              // 2048 float4 slots
        int r = id>>4; int k4 = (id&15)*4;
        int row = rowBase + r; if (row >= NN) row = NN-1;
        float4 v = *(const float4*)&x[(size_t)row*INF + k4];
        *(unsigned int*)&Xs[r*72 + k4]     = pk2(v.x, v.y);
        *(unsigned int*)&Xs[r*72 + k4 + 2] = pk2(v.z, v.w);
    }
    __syncthreads();
    int lane = t & 63, w = t >> 6;
    int lr = lane & 15, quad = lane >> 4;
    f32x4 acc[2][8];
    #pragma unroll
    for (int i=0;i<2;i++)
        #pragma unroll
        for (int j=0;j<8;j++) acc[i][j] = (f32x4){0.f,0.f,0.f,0.f};
    #pragma unroll
    for (int ks=0; ks<2; ++ks){
        int kb = ks*32 + quad*8;
        short8 b0 = *(const short8*)&Xs[((w  )*16 + lr)*72 + kb];
        short8 b1 = *(const short8*)&Xs[((w+4)*16 + lr)*72 + kb];
        #pragma unroll
        for (int mt=0; mt<8; ++mt){
            short8 a = *(const short8*)&Ws[(mt*16 + lr)*72 + kb];
            acc[0][mt] = __builtin_amdgcn_mfma_f32_16x16x32_bf16(a, b0, acc[0][mt], 0, 0, 0);
            acc[1][mt] = __builtin_amdgcn_mfma_f32_16x16x32_bf16(a, b1, acc[1][mt], 0, 0, 0);
        }
    }
    #pragma unroll
    for (int rt=0; rt<2; ++rt){
        int row = rowBase + (w + rt*4)*16 + lr;
        if (row < NN){
            float dv = dinv[row];
            #pragma unroll
            for (int mt=0; mt<8; ++mt){
                int p = __builtin_amdgcn_cvt_pk_fp8_f32(acc[rt][mt][0]*dv, acc[rt][mt][1]*dv, 0, false);
                p     = __builtin_amdgcn_cvt_pk_fp8_f32(acc[rt][mt][2]*dv, acc[rt][mt][3]*dv, p, true);
                *(int*)&xws8[(size_t)row*F + mt*16 + quad*4] = p;
            }
        }
    }
}

// ---------------- binned scatter: relative cursors (bcursor zero-initialized by memset) ----------------
__global__ __launch_bounds__(1024) void k_scatter2(const int* __restrict__ ei, int* __restrict__ bcursor,
                                                   int* __restrict__ ebuf){
    __shared__ int lh[NB];
    __shared__ int lb[NB];
    int t = threadIdx.x;
    int base = blockIdx.x * SC_CHUNK;
    for (int b=t; b<NB; b+=1024) lh[b] = 0;
    __syncthreads();
    int rr[4], cc[4];
    #pragma unroll
    for (int q=0;q<4;q++){
        int i = t + q*1024;
        bool v = (i < SC_CHUNK);
        int idx = v ? (base + i) : base;
        rr[q] = ei[idx];
        cc[q] = ei[NE + idx];
        if (v) atomicAdd(&lh[cc[q]>>7], 1);
    }
    __syncthreads();
    for (int b=t; b<NB; b+=1024){
        int n = lh[b];
        lb[b] = n ? (b*BCAP + atomicAdd(&bcursor[b], n)) : 0;
        lh[b] = 0;
    }
    __syncthreads();
    #pragma unroll
    for (int q=0;q<4;q++){
        int i = t + q*1024;
        if (i < SC_CHUNK){
            int b = cc[q] >> 7;
            int rk = atomicAdd(&lh[b], 1);
            ebuf[lb[b] + rk] = (rr[q] << 7) | (cc[q] & 127);
        }
    }
}

// ---------------- per-bucket counting sort; LDS-staged output ----------------
__global__ __launch_bounds__(256) void k_sort(const int* __restrict__ ebuf, const int* __restrict__ bcursor,
                                              int* __restrict__ cnt, float* __restrict__ dinv,
                                              int* __restrict__ nstart, int* __restrict__ ebuf2){
    __shared__ int lh[128];
    __shared__ int s[128];
    __shared__ int lcur[128];
    __shared__ int sorted[BCAP];
    int t = threadIdx.x;
    int b = blockIdx.x;
    int e0 = b * BCAP;
    int nE = bcursor[b];          // relative count
    if (t < 128) lh[t] = 0;
    __syncthreads();
    for (int i=t; i<nE; i+=256) atomicAdd(&lh[ebuf[e0+i] & 127], 1);
    __syncthreads();
    int c = (t < 128) ? lh[t] : 0;
    if (t < 128) s[t] = c;
    __syncthreads();
    #pragma unroll
    for (int off=1; off<128; off<<=1){
        int v = (t >= off && t < 128) ? s[t-off] : 0;
        __syncthreads();
        if (t < 128) s[t] += v;
        __syncthreads();
    }
    int node = b*128 + t;
    if (t < 128){
        int excl = s[t] - c;
        lcur[t] = excl;
        if (node < NN){
            nstart[node] = e0 + excl;
            cnt[node] = c;
            dinv[node] = rsqrtf((float)c + 2.0f);
        }
    }
    __syncthreads();
    for (int i=t; i<nE; i+=256){
        int v = ebuf[e0 + i];
        int nl = v & 127;
        int rk = atomicAdd(&lcur[nl], 1);
        sorted[rk] = (v >> 7) << 5;   // row * 32 (uint-word offset into xws8)
    }
    __syncthreads();
    for (int i=t; i<nE; i+=256) ebuf2[e0 + i] = sorted[i];
}

// ---------------- fused: CSR gather + GCN epilogue + BN + ReLU -> h,hb + pool -> z, znb ----------------
__global__ __launch_bounds__(256) void k_aggpool(const unsigned char* __restrict__ xws8,
                                                 const int* __restrict__ nstart, const int* __restrict__ cnt,
                                                 const float* __restrict__ dinv, const float* __restrict__ b_gcn,
                                                 const float* __restrict__ bn_g, const float* __restrict__ bn_b,
                                                 const int* __restrict__ ebuf2,
                                                 const float* __restrict__ lnpre_g, const float* __restrict__ lnpre_b,
                                                 float* __restrict__ h, unsigned short* __restrict__ hb,
                                                 float* __restrict__ z, unsigned short* __restrict__ znb){
    __shared__ float zacc[4][128];
    int t = threadIdx.x;
    int lane = t & 63, w = t >> 6;
    int half = lane >> 5, lh = lane & 31;
    int g = blockIdx.x;
    const unsigned int* xw32 = (const unsigned int*)xws8;   // row stride = 32 uints
    unsigned int* hb32 = (unsigned int*)hb;
    unsigned int* znb32 = (unsigned int*)znb;

    float4 bg4  = *(const float4*)&b_gcn[4*lh];
    float4 bng4 = *(const float4*)&bn_g[4*lh];
    float4 bnb4 = *(const float4*)&bn_b[4*lh];
    const float bns = rsqrtf(1.f + 1e-5f);

    float za0=0.f, za1=0.f, za2=0.f, za3=0.f;

    for (int i = w; i < 50; i += 4){
        int node = g*50 + i;
        int s0n = nstart[node]; int dg = cnt[node]; float dv = dinv[node];
        unsigned int us = xw32[node*32 + lh];   // self-loop, issued early
        float a0=0.f, a1=0.f, a2=0.f, a3=0.f;
        int j=0;
        for (; j+8<=dg; j+=8){
            int r0 = ebuf2[s0n+j+0+half];
            int r1 = ebuf2[s0n+j+2+half];
            int r2 = ebuf2[s0n+j+4+half];
            int r3 = ebuf2[s0n+j+6+half];
            unsigned int u0 = xw32[r0 + lh];
            unsigned int u1 = xw32[r1 + lh];
            unsigned int u2 = xw32[r2 + lh];
            unsigned int u3 = xw32[r3 + lh];
            f32x2 l0 = __builtin_amdgcn_cvt_pk_f32_fp8(u0, false);
            f32x2 h0 = __builtin_amdgcn_cvt_pk_f32_fp8(u0, true);
            f32x2 l1 = __builtin_amdgcn_cvt_pk_f32_fp8(u1, false);
            f32x2 h1 = __builtin_amdgcn_cvt_pk_f32_fp8(u1, true);
            f32x2 l2 = __builtin_amdgcn_cvt_pk_f32_fp8(u2, false);
            f32x2 h2 = __builtin_amdgcn_cvt_pk_f32_fp8(u2, true);
            f32x2 l3 = __builtin_amdgcn_cvt_pk_f32_fp8(u3, false);
            f32x2 h3 = __builtin_amdgcn_cvt_pk_f32_fp8(u3, true);
            a0 += (l0.x + l1.x) + (l2.x + l3.x);
            a1 += (l0.y + l1.y) + (l2.y + l3.y);
            a2 += (h0.x + h1.x) + (h2.x + h3.x);
            a3 += (h0.y + h1.y) + (h2.y + h3.y);
        }
        for (; j+2<=dg; j+=2){
            int r0 = ebuf2[s0n+j+half];
            unsigned int u0 = xw32[r0 + lh];
            f32x2 l0 = __builtin_amdgcn_cvt_pk_f32_fp8(u0, false);
            f32x2 h0 = __builtin_amdgcn_cvt_pk_f32_fp8(u0, true);
            a0 += l0.x; a1 += l0.y; a2 += h0.x; a3 += h0.y;
        }
        if (j < dg && half == 0){
            int r0 = ebuf2[s0n+j];
            unsigned int u0 = xw32[r0 + lh];
            f32x2 l0 = __builtin_amdgcn_cvt_pk_f32_fp8(u0, false);
            f32x2 h0 = __builtin_amdgcn_cvt_pk_f32_fp8(u0, true);
            a0 += l0.x; a1 += l0.y; a2 += h0.x; a3 += h0.y;
        }
        a0 += __shfl_xor(a0, 32);
        a1 += __shfl_xor(a1, 32);
        a2 += __shfl_xor(a2, 32);
        a3 += __shfl_xor(a3, 32);
        f32x2 fl = __builtin_amdgcn_cvt_pk_f32_fp8(us, false);
        f32x2 fh = __builtin_amdgcn_cvt_pk_f32_fp8(us, true);
        float p0 = dv*(a0 + 2.f*fl.x) + bg4.x;
        float p1 = dv*(a1 + 2.f*fl.y) + bg4.y;
        float p2 = dv*(a2 + 2.f*fh.x) + bg4.z;
        float p3 = dv*(a3 + 2.f*fh.y) + bg4.w;
        p0 = fmaxf(p0*bns*bng4.x + bnb4.x, 0.f);
        p1 = fmaxf(p1*bns*bng4.y + bnb4.y, 0.f);
        p2 = fmaxf(p2*bns*bng4.z + bnb4.z, 0.f);
        p3 = fmaxf(p3*bns*bng4.w + bnb4.w, 0.f);
        if (half == 0){
            *(float4*)&h[(size_t)node*F + 4*lh] = make_float4(p0,p1,p2,p3);
            *(uint2*)&hb32[(size_t)node*64 + 2*lh] = make_uint2(pk2(p0,p1), pk2(p2,p3));
        }
        za0 += p0; za1 += p1; za2 += p2; za3 += p3;
    }
    if (half == 0)
        *(float4*)&zacc[w][4*lh] = make_float4(za0, za1, za2, za3);
    __syncthreads();
    if (w == 0){
        float4 v0 = *(const float4*)&zacc[0][4*lh];
        float4 v1 = *(const float4*)&zacc[1][4*lh];
        float4 v2 = *(const float4*)&zacc[2][4*lh];
        float4 v3 = *(const float4*)&zacc[3][4*lh];
        float s0 = ((v0.x+v1.x)+(v2.x+v3.x)) / 50.0f;
        float s1 = ((v0.y+v1.y)+(v2.y+v3.y)) / 50.0f;
        float s2 = ((v0.z+v1.z)+(v2.z+v3.z)) / 50.0f;
        float s3 = ((v0.w+v1.w)+(v2.w+v3.w)) / 50.0f;
        if (half == 0)
            *(float4*)&z[(size_t)g*F + 4*lh] = make_float4(s0,s1,s2,s3);
        float s = (s0+s1)+(s2+s3);
        #pragma unroll
        for (int off=1; off<32; off<<=1) s += __shfl_xor(s, off);
        float m = s * (1.f/128.f);
        float d0=s0-m, d1=s1-m, d2=s2-m, d3=s3-m;
        float vv = (d0*d0+d1*d1)+(d2*d2+d3*d3);
        #pragma unroll
        for (int off=1; off<32; off<<=1) vv += __shfl_xor(vv, off);
        float rs = rsqrtf(vv*(1.f/128.f) + 1e-5f);
        float4 lg = *(const float4*)&lnpre_g[4*lh];
        float4 lb = *(const float4*)&lnpre_b[4*lh];
        if (half == 0){
            float o0 = d0*rs*lg.x+lb.x, o1 = d1*rs*lg.y+lb.y;
            float o2 = d2*rs*lg.z+lb.z, o3 = d3*rs*lg.w+lb.w;
            *(uint2*)&znb32[(size_t)g*64 + 2*lh] = make_uint2(pk2(o0,o1), pk2(o2,o3));
        }
    }
}

// ---------------- fused set-transformer v2: round-9's VERIFIED stage structure,
//                  but MFMA B-operands stream directly from global bf16 tables (no Bw staging).
// bf16 LDS tiles: stride 136 shorts; fp32 tiles: stride 132 floats.
// LDS overlay (bytes):
//   [0..41600)       Sc    float[4][50][52]  (attn only)
//   [41600..68000)   qs | zd1f  float[50][132]
//   [68000..94400)   ks ;  zd1b short[64][136]   (ks dead after attn)
//   [94400..120800)  vs ;  f1b/zd2b short[64][136] (vs dead after attn)
//   [120800..138208) aob   short[64][136]
__global__ __launch_bounds__(256) void k_settf2(const unsigned short* __restrict__ znb,
                                                const float* __restrict__ z,
                                                const unsigned short* __restrict__ Wqb,
                                                const unsigned short* __restrict__ Wkb,
                                                const unsigned short* __restrict__ Wvb,
                                                const float* __restrict__ bq, const float* __restrict__ bk,
                                                const float* __restrict__ bv,
                                                const unsigned short* __restrict__ Wob, const float* __restrict__ bo,
                                                const float* __restrict__ ln1_g, const float* __restrict__ ln1_b,
                                                const unsigned short* __restrict__ W1b, const float* __restrict__ b1,
                                                const unsigned short* __restrict__ W2b, const float* __restrict__ b2,
                                                const float* __restrict__ ln2_g, const float* __restrict__ ln2_b,
                                                const unsigned short* __restrict__ Wgbotb, const float* __restrict__ bg,
                                                float* __restrict__ zd2, float* __restrict__ gsi){
    __shared__ __align__(16) char smem[138208];
    float* Sc   = (float*)smem;
    float* qs   = (float*)(smem + 41600);
    float* ks   = (float*)(smem + 68000);
    float* vs   = (float*)(smem + 94400);
    short* aob  = (short*)(smem + 120800);
    float* zd1f = (float*)(smem + 41600);
    short* zd1b = (short*)(smem + 68000);
    short* f1b  = (short*)(smem + 94400);
    short* zd2b = f1b;

    int t = threadIdx.x;
    int lane = t & 63, w = t >> 6;
    int lr = lane & 15, quad = lane >> 4;
    int s = blockIdx.x;
    const int r0 = s*50;

    // ---- stage 1: QKV (A from global znb, B from global tables, fp32 out to LDS) ----
    {
        int rl = w*16 + lr; if (rl > 49) rl = 49;
        const unsigned short* arow = &znb[(size_t)(r0 + rl)*F];
        for (int zsel=0; zsel<3; ++zsel){
            const unsigned short* B = (zsel==0)?Wqb:(zsel==1)?Wkb:Wvb;
            const float* bp = (zsel==0)?bq:(zsel==1)?bk:bv;
            float* outp = (zsel==0)?qs:(zsel==1)?ks:vs;
            f32x4 acc[8];
            #pragma unroll
            for (int j=0;j<8;j++) acc[j] = (f32x4){0.f,0.f,0.f,0.f};
            #pragma unroll
            for (int ks4=0; ks4<4; ++ks4){
                int kb = ks4*32 + quad*8;
                short8 a = *(const short8*)&arow[kb];
                #pragma unroll
                for (int nt=0; nt<8; ++nt){
                    short8 b = *(const short8*)&B[(size_t)(nt*16 + lr)*128 + kb];
                    acc[nt] = __builtin_amdgcn_mfma_f32_16x16x32_bf16(a, b, acc[nt], 0, 0, 0);
                }
            }
            #pragma unroll
            for (int r=0; r<4; ++r){
                int row = w*16 + quad*4 + r;
                if (row < 50){
                    #pragma unroll
                    for (int nt=0; nt<8; ++nt){
                        int col = nt*16 + lr;
                        outp[row*132 + col] = acc[nt][r] + bp[col];
                    }
                }
            }
        }
    }
    __syncthreads();

    // ---- stage 2: attention, one wave per head (verified round-9 body) ----
    {
        int hh = w;
        float* ScH = Sc + hh*50*52;
        int qi = lane;
        if (qi < 50){
            float qreg[32];
            #pragma unroll
            for (int d=0; d<32; ++d) qreg[d] = qs[qi*132 + hh*32 + d];
            for (int ki=0; ki<50; ++ki){
                float acc=0.f;
                #pragma unroll
                for (int d=0; d<32; ++d) acc += qreg[d] * ks[ki*132 + hh*32 + d];
                ScH[qi*52 + ki] = acc * 0.17677669529663687f;
            }
            float m=-1e30f;
            for (int ki=0; ki<50; ++ki) m = fmaxf(m, ScH[qi*52+ki]);
            float sum=0.f;
            for (int ki=0; ki<50; ++ki){ float e=__expf(ScH[qi*52+ki]-m); ScH[qi*52+ki]=e; sum+=e; }
            float inv = 1.f/sum;
            float o[32];
            #pragma unroll
            for (int d=0; d<32; ++d) o[d] = 0.f;
            for (int ki=0; ki<50; ++ki){
                float sc = ScH[qi*52+ki] * inv;
                #pragma unroll
                for (int d=0; d<32; ++d) o[d] += sc * vs[ki*132 + hh*32 + d];
            }
            #pragma unroll
            for (int d=0; d<32; ++d) aob[qi*136 + hh*32 + d] = f2bs(o[d]);
        } else if (qi < 64){
            #pragma unroll
            for (int d=0; d<32; ++d) aob[qi*136 + hh*32 + d] = 0;
        }
    }
    __syncthreads();

    // ---- stage 3: ap = ao@Wo + bo; zd1 = LN1(z + ap) -> zd1f (fp32) + zd1b (bf16) ----
    {
        f32x4 acc[8];
        #pragma unroll
        for (int j=0;j<8;j++) acc[j] = (f32x4){0.f,0.f,0.f,0.f};
        #pragma unroll
        for (int ks4=0; ks4<4; ++ks4){
            int kb = ks4*32 + quad*8;
            short8 a = *(const short8*)&aob[(w*16 + lr)*136 + kb];
            #pragma unroll
            for (int nt=0; nt<8; ++nt){
                short8 b = *(const short8*)&Wob[(size_t)(nt*16 + lr)*128 + kb];
                acc[nt] = __builtin_amdgcn_mfma_f32_16x16x32_bf16(a, b, acc[nt], 0, 0, 0);
            }
        }
        // qs/ks regions dead since stage-2 barrier; safe to write zd1f/zd1b now.
        #pragma unroll
        for (int r=0; r<4; ++r){
            int row = w*16 + quad*4 + r;
            float v[8];
            if (row < 50){
                #pragma unroll
                for (int nt=0; nt<8; ++nt){
                    int col = nt*16 + lr;
                    v[nt] = acc[nt][r] + bo[col] + z[(size_t)(r0+row)*F + col];
                }
            } else {
                #pragma unroll
                for (int nt=0; nt<8; ++nt) v[nt] = 0.f;
            }
            float ssum = 0.f;
            #pragma unroll
            for (int nt=0; nt<8; ++nt) ssum += v[nt];
            #pragma unroll
            for (int off=1; off<16; off<<=1) ssum += __shfl_xor(ssum, off);
            float mean = ssum * (1.f/128.f);
            float var = 0.f;
            float d[8];
            #pragma unroll
            for (int nt=0; nt<8; ++nt){ d[nt] = v[nt]-mean; var += d[nt]*d[nt]; }
            #pragma unroll
            for (int off=1; off<16; off<<=1) var += __shfl_xor(var, off);
            float rsv = rsqrtf(var*(1.f/128.f) + 1e-5f);
            if (row < 50){
                #pragma unroll
                for (int nt=0; nt<8; ++nt){
                    int col = nt*16 + lr;
                    float o = d[nt]*rsv*ln1_g[col] + ln1_b[col];
                    zd1f[row*132 + col] = o;
                    zd1b[row*136 + col] = f2bs(o);
                }
            } else {
                #pragma unroll
                for (int nt=0; nt<8; ++nt) zd1b[row*136 + nt*16 + lr] = 0;
            }
        }
    }
    __syncthreads();

    // ---- stage 4: FFN, 8 K-chunks of 128, acc2 in registers ----
    f32x4 acc2[8];
    #pragma unroll
    for (int j=0;j<8;j++) acc2[j] = (f32x4){0.f,0.f,0.f,0.f};
    for (int c=0; c<8; ++c){
        f32x4 a1[8];
        #pragma unroll
        for (int j=0;j<8;j++) a1[j] = (f32x4){0.f,0.f,0.f,0.f};
        #pragma unroll
        for (int ks4=0; ks4<4; ++ks4){
            int kb = ks4*32 + quad*8;
            short8 a = *(const short8*)&zd1b[(w*16 + lr)*136 + kb];
            #pragma unroll
            for (int nt=0; nt<8; ++nt){
                short8 b = *(const short8*)&W1b[(size_t)(c*128 + nt*16 + lr)*128 + kb];
                a1[nt] = __builtin_amdgcn_mfma_f32_16x16x32_bf16(a, b, a1[nt], 0, 0, 0);
            }
        }
        #pragma unroll
        for (int r=0; r<4; ++r){
            int row = w*16 + quad*4 + r;
            #pragma unroll
            for (int nt=0; nt<8; ++nt){
                int col = nt*16 + lr;
                f1b[row*136 + col] = f2bs(fmaxf(a1[nt][r] + b1[c*128 + col], 0.f));
            }
        }
        __syncthreads();
        #pragma unroll
        for (int ks4=0; ks4<4; ++ks4){
            int kb = ks4*32 + quad*8;
            short8 a = *(const short8*)&f1b[(w*16 + lr)*136 + kb];
            #pragma unroll
            for (int nt=0; nt<8; ++nt){
                short8 b = *(const short8*)&W2b[(size_t)(nt*16 + lr)*1024 + c*128 + kb];
                acc2[nt] = __builtin_amdgcn_mfma_f32_16x16x32_bf16(a, b, acc2[nt], 0, 0, 0);
            }
        }
        __syncthreads();
    }

    // ---- stage 5: zd2 = LN2(zd1 + ffn + b2); gsi = zd2 @ Wg_bot + bg ----
    {
        #pragma unroll
        for (int r=0; r<4; ++r){
            int row = w*16 + quad*4 + r;
            float v[8];
            if (row < 50){
                #pragma unroll
                for (int nt=0; nt<8; ++nt){
                    int col = nt*16 + lr;
                    v[nt] = acc2[nt][r] + b2[col] + zd1f[row*132 + col];
                }
            } else {
                #pragma unroll
                for (int nt=0; nt<8; ++nt) v[nt] = 0.f;
            }
            float ssum = 0.f;
            #pragma unroll
            for (int nt=0; nt<8; ++nt) ssum += v[nt];
            #pragma unroll
            for (int off=1; off<16; off<<=1) ssum += __shfl_xor(ssum, off);
            float mean = ssum * (1.f/128.f);
            float var = 0.f;
            float d[8];
            #pragma unroll
            for (int nt=0; nt<8; ++nt){ d[nt] = v[nt]-mean; var += d[nt]*d[nt]; }
            #pragma unroll
            for (int off=1; off<16; off<<=1) var += __shfl_xor(var, off);
            float rsv = rsqrtf(var*(1.f/128.f) + 1e-5f);
            if (row < 50){
                #pragma unroll
                for (int nt=0; nt<8; ++nt){
                    int col = nt*16 + lr;
                    float o = d[nt]*rsv*ln2_g[col] + ln2_b[col];
                    zd2[(size_t)(r0+row)*F + col] = o;
                    zd2b[row*136 + col] = f2bs(o);
                }
            } else {
                #pragma unroll
                for (int nt=0; nt<8; ++nt) zd2b[row*136 + nt*16 + lr] = 0;
            }
        }
        __syncthreads();
        f32x4 ag[8];
        #pragma unroll
        for (int j=0;j<8;j++) ag[j] = (f32x4){0.f,0.f,0.f,0.f};
        #pragma unroll
        for (int ks4=0; ks4<4; ++ks4){
            int kb = ks4*32 + quad*8;
            short8 a = *(const short8*)&zd2b[(w*16 + lr)*136 + kb];
            #pragma unroll
            for (int nt=0; nt<8; ++nt){
                short8 b = *(const short8*)&Wgbotb[(size_t)(nt*16 + lr)*128 + kb];
                ag[nt] = __builtin_amdgcn_mfma_f32_16x16x32_bf16(a, b, ag[nt], 0, 0, 0);
            }
        }
        #pragma unroll
        for (int r=0; r<4; ++r){
            int row = w*16 + quad*4 + r;
            if (row < 50){
                #pragma unroll
                for (int nt=0; nt<8; ++nt){
                    int col = nt*16 + lr;
                    gsi[(size_t)(r0+row)*F + col] = ag[nt][r] + bg[col];
                }
            }
        }
    }
}

// ---------------- MFMA gate: 64-row tiles, B from global bf16 Wgb (no LDS, no barriers) ----------------
__global__ __launch_bounds__(256) void k_gate_mfma(const float* __restrict__ h,
                                                   const unsigned short* __restrict__ hb,
                                                   const unsigned short* __restrict__ Wgb,
                                                   const float* __restrict__ gsi, const float* __restrict__ zd2,
                                                   float* __restrict__ out){
    int t = threadIdx.x;
    int lane = t & 63, w = t >> 6;
    int lr = lane & 15, quad = lane >> 4;
    int mrow0 = blockIdx.x*64 + w*16;
    f32x4 acc[8];
    #pragma unroll
    for (int j=0;j<8;j++) acc[j] = (f32x4){0.f,0.f,0.f,0.f};
    #pragma unroll
    for (int ks=0; ks<4; ++ks){
        int kb = ks*32 + quad*8;
        int row = mrow0 + lr;
        if (row >= NN) row = NN-1;
        short8 a = *(const short8*)&hb[(size_t)row*F + kb];
        #pragma unroll
        for (int nt=0; nt<8; ++nt){
            short8 b = *(const short8*)&Wgb[(size_t)(nt*16 + lr)*128 + kb];
            acc[nt] = __builtin_amdgcn_mfma_f32_16x16x32_bf16(a, b, acc[nt], 0, 0, 0);
        }
    }
    #pragma unroll
    for (int r=0; r<4; ++r){
        int row = mrow0 + quad*4 + r;
        if (row >= NN) continue;
        int g = row / 50;
        const float* gs = &gsi[(size_t)g*F];
        const float* zs = &zd2[(size_t)g*F];
        const float* hr = &h[(size_t)row*F];
        float* orow = &out[(size_t)row*F];
        #pragma unroll
        for (int nt=0; nt<8; ++nt){
            int col = nt*16 + lr;
            float L = acc[nt][r] + gs[col];
            float gate = 1.f/(1.f + __expf(-L));
            orow[col] = gate*zs[col] + (1.f-gate)*hr[col];
        }
    }
}

extern "C" void kernel_launch(void* const* d_in, const int* in_sizes, int n_in,
                              void* d_out, int out_size, void* d_ws, size_t ws_size,
                              hipStream_t stream) {
    const float* x      = (const float*)d_in[0];
    const int*   ei     = (const int*)d_in[1];
    const float* W_gcn  = (const float*)d_in[4];
    const float* b_gcn  = (const float*)d_in[5];
    const float* bn_g   = (const float*)d_in[6];
    const float* bn_b   = (const float*)d_in[7];
    const float* lnpre_g= (const float*)d_in[8];
    const float* lnpre_b= (const float*)d_in[9];
    const float* Wq     = (const float*)d_in[10];
    const float* bq     = (const float*)d_in[11];
    const float* Wk     = (const float*)d_in[12];
    const float* bk     = (const float*)d_in[13];
    const float* Wv     = (const float*)d_in[14];
    const float* bv     = (const float*)d_in[15];
    const float* Wo     = (const float*)d_in[16];
    const float* bo     = (const float*)d_in[17];
    const float* ln1_g  = (const float*)d_in[18];
    const float* ln1_b  = (const float*)d_in[19];
    const float* W1     = (const float*)d_in[20];
    const float* b1     = (const float*)d_in[21];
    const float* W2     = (const float*)d_in[22];
    const float* b2     = (const float*)d_in[23];
    const float* ln2_g  = (const float*)d_in[24];
    const float* ln2_b  = (const float*)d_in[25];
    const float* Wg     = (const float*)d_in[26];
    const float* bg     = (const float*)d_in[27];
    float* out = (float*)d_out;
    char* ws = (char*)d_ws;

    // workspace layout
    size_t o = 0;
    unsigned char* xws8 = (unsigned char*)(ws + o); o += (size_t)NN*F; // 12.8 MB (fp8)
    float* h     = (float*)(ws + o); o += (size_t)NN*F*4;            // 51.2 MB
    unsigned short* hb = (unsigned short*)(ws + o); o += (size_t)NN*F*2; // 25.6 MB (bf16)
    int*   cnt   = (int*)(ws + o);   o += (size_t)NN*4;
    int*   nstart= (int*)(ws + o);   o += (size_t)NN*4;
    int*   ebuf  = (int*)(ws + o);   o += (size_t)NB*BCAP*4;         // 9.6 MB
    int*   ebuf2 = (int*)(ws + o);   o += (size_t)NB*BCAP*4;         // 9.6 MB
    float* dinv  = (float*)(ws + o); o += (size_t)NN*4;
    int*   bcursor=(int*)(ws + o);   o += 1024*4;
    unsigned short* Wgb    = (unsigned short*)(ws + o); o += 16384*2;
    unsigned short* Wqb    = (unsigned short*)(ws + o); o += 16384*2;
    unsigned short* Wkb    = (unsigned short*)(ws + o); o += 16384*2;
    unsigned short* Wvb    = (unsigned short*)(ws + o); o += 16384*2;
    unsigned short* Wob    = (unsigned short*)(ws + o); o += 16384*2;
    unsigned short* Wgbotb = (unsigned short*)(ws + o); o += 16384*2;
    unsigned short* W1b = (unsigned short*)(ws + o); o += (size_t)131072*2;  // 256 KB
    unsigned short* W2b = (unsigned short*)(ws + o); o += (size_t)131072*2;  // 256 KB
    float* z     = (float*)(ws + o); o += (size_t)NG*F*4;
    unsigned short* znb = (unsigned short*)(ws + o); o += (size_t)NG*F*2;
    float* zd2   = (float*)(ws + o); o += (size_t)NG*F*4;
    float* gsi   = (float*)(ws + o); o += (size_t)NG*F*4;

    // ---- GCN phase (5 dispatches incl. memset) ----
    hipMemsetAsync(bcursor, 0, (size_t)NB*4, stream);
    k_scatter2<<<SC_BLOCKS, 1024, 0, stream>>>(ei, bcursor, ebuf);
    k_sort<<<NB, 256, 0, stream>>>(ebuf, bcursor, cnt, dinv, nstart, ebuf2);
    k_xws<<<NXB + NWB, 256, 0, stream>>>(x, W_gcn, dinv, xws8,
                                         Wq, Wk, Wv, Wo, W1, W2, Wg,
                                         Wqb, Wkb, Wvb, Wob, W1b, W2b, Wgb, Wgbotb);
    k_aggpool<<<NG, 256, 0, stream>>>(xws8, nstart, cnt, dinv, b_gcn, bn_g, bn_b, ebuf2,
                                      lnpre_g, lnpre_b, h, hb, z, znb);

    // ---- fused set transformer (one dispatch, direct-global weight tables) ----
    k_settf2<<<NS, 256, 0, stream>>>(znb, z, Wqb, Wkb, Wvb, bq, bk, bv,
                                     Wob, bo, ln1_g, ln1_b, W1b, b1, W2b, b2,
                                     ln2_g, ln2_b, Wgbotb, bg, zd2, gsi);

    // ---- gated fusion -> output ----
    k_gate_mfma<<<(NN+63)/64, 256, 0, stream>>>(h, hb, Wgb, gsi, zd2, out);
}

// Round 13
// 312.921 us; speedup vs baseline: 1.8524x; 1.1933x over previous
//
#include <hip/hip_runtime.h>
#include <hip/hip_bf16.h>
#include <cstddef>

#define NN 100000
#define NE 1600000
#define NG 2000
#define NS 40
#define INF 64
#define F 128
#define FFN_DIM 1024
#define NB 782            // ceil(100000/128) buckets of 128 nodes
#define BCAP 3072         // fixed bucket capacity (mean 2048, sigma 45 -> 19+ sigma margin)
#define SC_BLOCKS 512
#define SC_CHUNK 3125     // 512*3125 = 1.6M edges exactly
#define NXB 782           // xws row-tiles
#define NWB 72            // weight-conversion blocks appended to k_xws grid

using bf16 = __hip_bfloat16;
typedef __attribute__((ext_vector_type(8))) short short8;
typedef __attribute__((ext_vector_type(4))) float f32x4;
typedef __attribute__((ext_vector_type(2))) float f32x2;

__device__ __forceinline__ short f2bs(float f){
    union { bf16 b; short s; } u; u.b = __float2bfloat16(f); return u.s;
}
__device__ __forceinline__ unsigned int pk2(float a, float b){
    return (unsigned int)(unsigned short)f2bs(a) | ((unsigned int)(unsigned short)f2bs(b) << 16);
}

// ---------------- xws = (x @ W_gcn) * dinv[row] -> fp8, PLUS weight-table conversion ----------------
__global__ __launch_bounds__(256) void k_xws(const float* __restrict__ x, const float* __restrict__ W,
                                             const float* __restrict__ dinv, unsigned char* __restrict__ xws8,
                                             const float* __restrict__ Wo, const float* __restrict__ W1,
                                             const float* __restrict__ W2, const float* __restrict__ Wg,
                                             unsigned short* __restrict__ Wob, unsigned short* __restrict__ W1b,
                                             unsigned short* __restrict__ W2b, unsigned short* __restrict__ Wgb,
                                             unsigned short* __restrict__ Wgbotb){
    int t = threadIdx.x;
    if (blockIdx.x >= NXB){
        int wt = (blockIdx.x - NXB)*256 + t;
        const int ws = NWB*256;
        for (int i=wt; i<16384; i+=ws){
            int k = i>>7, n = i&127;
            Wob[n*128+k]    = (unsigned short)f2bs(Wo[(size_t)k*F+n]);
            Wgb[n*128+k]    = (unsigned short)f2bs(Wg[(size_t)k*F+n]);
            Wgbotb[n*128+k] = (unsigned short)f2bs(Wg[(size_t)(F+k)*F+n]);
        }
        for (int i=wt; i<131072; i+=ws){
            int k = i>>10, n = i&1023;
            W1b[(size_t)n*128+k] = (unsigned short)f2bs(W1[(size_t)k*FFN_DIM+n]);
        }
        for (int i=wt; i<131072; i+=ws){
            int n = i>>10, k = i&1023;
            W2b[(size_t)n*1024+k] = (unsigned short)f2bs(W2[(size_t)k*F+n]);
        }
        return;
    }
    __shared__ short Xs[128*72];   // [row][k], stride 72 (K=64)
    __shared__ short Ws[128*72];   // [feature][k], stride 72
    int rowBase = blockIdx.x * 128;
    #pragma unroll
    for (int i=0;i<32;i++){
        int id = i*256+t; int k = id>>7, n = id&127;
        Ws[n*72 + k] = f2bs(W[id]);
    }
    #pragma unroll
    for (int i=0;i<8;i++){
        int id = i*256+t;              // 2048 float4 slots
        int r = id>>4; int k4 = (id&15)*4;
        int row = rowBase + r; if (row >= NN) row = NN-1;
        float4 v = *(const float4*)&x[(size_t)row*INF + k4];
        *(unsigned int*)&Xs[r*72 + k4]     = pk2(v.x, v.y);
        *(unsigned int*)&Xs[r*72 + k4 + 2] = pk2(v.z, v.w);
    }
    __syncthreads();
    int lane = t & 63, w = t >> 6;
    int lr = lane & 15, quad = lane >> 4;
    f32x4 acc[2][8];
    #pragma unroll
    for (int i=0;i<2;i++)
        #pragma unroll
        for (int j=0;j<8;j++) acc[i][j] = (f32x4){0.f,0.f,0.f,0.f};
    #pragma unroll
    for (int ks=0; ks<2; ++ks){
        int kb = ks*32 + quad*8;
        short8 b0 = *(const short8*)&Xs[((w  )*16 + lr)*72 + kb];
        short8 b1 = *(const short8*)&Xs[((w+4)*16 + lr)*72 + kb];
        #pragma unroll
        for (int mt=0; mt<8; ++mt){
            short8 a = *(const short8*)&Ws[(mt*16 + lr)*72 + kb];
            acc[0][mt] = __builtin_amdgcn_mfma_f32_16x16x32_bf16(a, b0, acc[0][mt], 0, 0, 0);
            acc[1][mt] = __builtin_amdgcn_mfma_f32_16x16x32_bf16(a, b1, acc[1][mt], 0, 0, 0);
        }
    }
    #pragma unroll
    for (int rt=0; rt<2; ++rt){
        int row = rowBase + (w + rt*4)*16 + lr;
        if (row < NN){
            float dv = dinv[row];
            #pragma unroll
            for (int mt=0; mt<8; ++mt){
                int p = __builtin_amdgcn_cvt_pk_fp8_f32(acc[rt][mt][0]*dv, acc[rt][mt][1]*dv, 0, false);
                p     = __builtin_amdgcn_cvt_pk_fp8_f32(acc[rt][mt][2]*dv, acc[rt][mt][3]*dv, p, true);
                *(int*)&xws8[(size_t)row*F + mt*16 + quad*4] = p;
            }
        }
    }
}

// ---------------- binned scatter: relative cursors (bcursor zero-initialized by memset) ----------------
__global__ __launch_bounds__(1024) void k_scatter2(const int* __restrict__ ei, int* __restrict__ bcursor,
                                                   int* __restrict__ ebuf){
    __shared__ int lh[NB];
    __shared__ int lb[NB];
    int t = threadIdx.x;
    int base = blockIdx.x * SC_CHUNK;
    for (int b=t; b<NB; b+=1024) lh[b] = 0;
    __syncthreads();
    int rr[4], cc[4];
    #pragma unroll
    for (int q=0;q<4;q++){
        int i = t + q*1024;
        bool v = (i < SC_CHUNK);
        int idx = v ? (base + i) : base;
        rr[q] = ei[idx];
        cc[q] = ei[NE + idx];
        if (v) atomicAdd(&lh[cc[q]>>7], 1);
    }
    __syncthreads();
    for (int b=t; b<NB; b+=1024){
        int n = lh[b];
        lb[b] = n ? (b*BCAP + atomicAdd(&bcursor[b], n)) : 0;
        lh[b] = 0;
    }
    __syncthreads();
    #pragma unroll
    for (int q=0;q<4;q++){
        int i = t + q*1024;
        if (i < SC_CHUNK){
            int b = cc[q] >> 7;
            int rk = atomicAdd(&lh[b], 1);
            ebuf[lb[b] + rk] = (rr[q] << 7) | (cc[q] & 127);
        }
    }
}

// ---------------- per-bucket counting sort; LDS-staged output ----------------
__global__ __launch_bounds__(256) void k_sort(const int* __restrict__ ebuf, const int* __restrict__ bcursor,
                                              int* __restrict__ cnt, float* __restrict__ dinv,
                                              int* __restrict__ nstart, int* __restrict__ ebuf2){
    __shared__ int lh[128];
    __shared__ int s[128];
    __shared__ int lcur[128];
    __shared__ int sorted[BCAP];
    int t = threadIdx.x;
    int b = blockIdx.x;
    int e0 = b * BCAP;
    int nE = bcursor[b];          // relative count
    if (t < 128) lh[t] = 0;
    __syncthreads();
    for (int i=t; i<nE; i+=256) atomicAdd(&lh[ebuf[e0+i] & 127], 1);
    __syncthreads();
    int c = (t < 128) ? lh[t] : 0;
    if (t < 128) s[t] = c;
    __syncthreads();
    #pragma unroll
    for (int off=1; off<128; off<<=1){
        int v = (t >= off && t < 128) ? s[t-off] : 0;
        __syncthreads();
        if (t < 128) s[t] += v;
        __syncthreads();
    }
    int node = b*128 + t;
    if (t < 128){
        int excl = s[t] - c;
        lcur[t] = excl;
        if (node < NN){
            nstart[node] = e0 + excl;
            cnt[node] = c;
            dinv[node] = rsqrtf((float)c + 2.0f);
        }
    }
    __syncthreads();
    for (int i=t; i<nE; i+=256){
        int v = ebuf[e0 + i];
        int nl = v & 127;
        int rk = atomicAdd(&lcur[nl], 1);
        sorted[rk] = (v >> 7) << 5;   // row * 32 (uint-word offset into xws8)
    }
    __syncthreads();
    for (int i=t; i<nE; i+=256) ebuf2[e0 + i] = sorted[i];
}

// ---------------- fused: CSR gather + GCN epilogue + BN + ReLU -> h,hb + pool + pre-LN + QKV ----------------
// QKV fold: zn broadcast via LDS; 384 fp32 dot-products per block (L2-hot weights).
__global__ __launch_bounds__(256) void k_aggpool(const unsigned char* __restrict__ xws8,
                                                 const int* __restrict__ nstart, const int* __restrict__ cnt,
                                                 const float* __restrict__ dinv, const float* __restrict__ b_gcn,
                                                 const float* __restrict__ bn_g, const float* __restrict__ bn_b,
                                                 const int* __restrict__ ebuf2,
                                                 const float* __restrict__ lnpre_g, const float* __restrict__ lnpre_b,
                                                 const float* __restrict__ Wq, const float* __restrict__ bq,
                                                 const float* __restrict__ Wk, const float* __restrict__ bk,
                                                 const float* __restrict__ Wv, const float* __restrict__ bv,
                                                 float* __restrict__ h, unsigned short* __restrict__ hb,
                                                 float* __restrict__ z,
                                                 float* __restrict__ qb, float* __restrict__ kb2,
                                                 float* __restrict__ vb){
    __shared__ float zacc[4][128];
    int t = threadIdx.x;
    int lane = t & 63, w = t >> 6;
    int half = lane >> 5, lh = lane & 31;
    int g = blockIdx.x;
    const unsigned int* xw32 = (const unsigned int*)xws8;   // row stride = 32 uints
    unsigned int* hb32 = (unsigned int*)hb;

    float4 bg4  = *(const float4*)&b_gcn[4*lh];
    float4 bng4 = *(const float4*)&bn_g[4*lh];
    float4 bnb4 = *(const float4*)&bn_b[4*lh];
    const float bns = rsqrtf(1.f + 1e-5f);

    float za0=0.f, za1=0.f, za2=0.f, za3=0.f;

    for (int i = w; i < 50; i += 4){
        int node = g*50 + i;
        int s0n = nstart[node]; int dg = cnt[node]; float dv = dinv[node];
        unsigned int us = xw32[node*32 + lh];   // self-loop, issued early
        float a0=0.f, a1=0.f, a2=0.f, a3=0.f;
        int j=0;
        for (; j+8<=dg; j+=8){
            int r0 = ebuf2[s0n+j+0+half];
            int r1 = ebuf2[s0n+j+2+half];
            int r2 = ebuf2[s0n+j+4+half];
            int r3 = ebuf2[s0n+j+6+half];
            unsigned int u0 = xw32[r0 + lh];
            unsigned int u1 = xw32[r1 + lh];
            unsigned int u2 = xw32[r2 + lh];
            unsigned int u3 = xw32[r3 + lh];
            f32x2 l0 = __builtin_amdgcn_cvt_pk_f32_fp8(u0, false);
            f32x2 h0 = __builtin_amdgcn_cvt_pk_f32_fp8(u0, true);
            f32x2 l1 = __builtin_amdgcn_cvt_pk_f32_fp8(u1, false);
            f32x2 h1 = __builtin_amdgcn_cvt_pk_f32_fp8(u1, true);
            f32x2 l2 = __builtin_amdgcn_cvt_pk_f32_fp8(u2, false);
            f32x2 h2 = __builtin_amdgcn_cvt_pk_f32_fp8(u2, true);
            f32x2 l3 = __builtin_amdgcn_cvt_pk_f32_fp8(u3, false);
            f32x2 h3 = __builtin_amdgcn_cvt_pk_f32_fp8(u3, true);
            a0 += (l0.x + l1.x) + (l2.x + l3.x);
            a1 += (l0.y + l1.y) + (l2.y + l3.y);
            a2 += (h0.x + h1.x) + (h2.x + h3.x);
            a3 += (h0.y + h1.y) + (h2.y + h3.y);
        }
        for (; j+2<=dg; j+=2){
            int r0 = ebuf2[s0n+j+half];
            unsigned int u0 = xw32[r0 + lh];
            f32x2 l0 = __builtin_amdgcn_cvt_pk_f32_fp8(u0, false);
            f32x2 h0 = __builtin_amdgcn_cvt_pk_f32_fp8(u0, true);
            a0 += l0.x; a1 += l0.y; a2 += h0.x; a3 += h0.y;
        }
        if (j < dg && half == 0){
            int r0 = ebuf2[s0n+j];
            unsigned int u0 = xw32[r0 + lh];
            f32x2 l0 = __builtin_amdgcn_cvt_pk_f32_fp8(u0, false);
            f32x2 h0 = __builtin_amdgcn_cvt_pk_f32_fp8(u0, true);
            a0 += l0.x; a1 += l0.y; a2 += h0.x; a3 += h0.y;
        }
        a0 += __shfl_xor(a0, 32);
        a1 += __shfl_xor(a1, 32);
        a2 += __shfl_xor(a2, 32);
        a3 += __shfl_xor(a3, 32);
        f32x2 fl = __builtin_amdgcn_cvt_pk_f32_fp8(us, false);
        f32x2 fh = __builtin_amdgcn_cvt_pk_f32_fp8(us, true);
        float p0 = dv*(a0 + 2.f*fl.x) + bg4.x;
        float p1 = dv*(a1 + 2.f*fl.y) + bg4.y;
        float p2 = dv*(a2 + 2.f*fh.x) + bg4.z;
        float p3 = dv*(a3 + 2.f*fh.y) + bg4.w;
        p0 = fmaxf(p0*bns*bng4.x + bnb4.x, 0.f);
        p1 = fmaxf(p1*bns*bng4.y + bnb4.y, 0.f);
        p2 = fmaxf(p2*bns*bng4.z + bnb4.z, 0.f);
        p3 = fmaxf(p3*bns*bng4.w + bnb4.w, 0.f);
        if (half == 0){
            *(float4*)&h[(size_t)node*F + 4*lh] = make_float4(p0,p1,p2,p3);
            *(uint2*)&hb32[(size_t)node*64 + 2*lh] = make_uint2(pk2(p0,p1), pk2(p2,p3));
        }
        za0 += p0; za1 += p1; za2 += p2; za3 += p3;
    }
    if (half == 0)
        *(float4*)&zacc[w][4*lh] = make_float4(za0, za1, za2, za3);
    __syncthreads();
    if (w == 0){
        float4 v0 = *(const float4*)&zacc[0][4*lh];
        float4 v1 = *(const float4*)&zacc[1][4*lh];
        float4 v2 = *(const float4*)&zacc[2][4*lh];
        float4 v3 = *(const float4*)&zacc[3][4*lh];
        float s0 = ((v0.x+v1.x)+(v2.x+v3.x)) / 50.0f;
        float s1 = ((v0.y+v1.y)+(v2.y+v3.y)) / 50.0f;
        float s2 = ((v0.z+v1.z)+(v2.z+v3.z)) / 50.0f;
        float s3 = ((v0.w+v1.w)+(v2.w+v3.w)) / 50.0f;
        if (half == 0)
            *(float4*)&z[(size_t)g*F + 4*lh] = make_float4(s0,s1,s2,s3);
        float s = (s0+s1)+(s2+s3);
        #pragma unroll
        for (int off=1; off<32; off<<=1) s += __shfl_xor(s, off);
        float m = s * (1.f/128.f);
        float d0=s0-m, d1=s1-m, d2=s2-m, d3=s3-m;
        float vv = (d0*d0+d1*d1)+(d2*d2+d3*d3);
        #pragma unroll
        for (int off=1; off<32; off<<=1) vv += __shfl_xor(vv, off);
        float rs = rsqrtf(vv*(1.f/128.f) + 1e-5f);
        float4 lg = *(const float4*)&lnpre_g[4*lh];
        float4 lb = *(const float4*)&lnpre_b[4*lh];
        if (half == 0){
            // zn row -> LDS broadcast buffer (reuse zacc[0]; this wave already consumed it)
            zacc[0][4*lh]   = d0*rs*lg.x+lb.x;
            zacc[0][4*lh+1] = d1*rs*lg.y+lb.y;
            zacc[0][4*lh+2] = d2*rs*lg.z+lb.z;
            zacc[0][4*lh+3] = d3*rs*lg.w+lb.w;
        }
    }
    __syncthreads();
    // ---- fused QKV: 384 dot-products (fp32), zn broadcast from LDS ----
    for (int idx = t; idx < 384; idx += 256){
        int sel = idx >> 7, col = idx & 127;
        const float* Wp = (sel==0) ? Wq : (sel==1) ? Wk : Wv;
        const float* bi = (sel==0) ? bq : (sel==1) ? bk : bv;
        float* C = (sel==0) ? qb : (sel==1) ? kb2 : vb;
        float acc = bi[col];
        #pragma unroll 4
        for (int k=0; k<128; ++k) acc += zacc[0][k] * Wp[(size_t)k*F + col];
        C[(size_t)g*F + col] = acc;
    }
}

// ---------------- attention: one block per (set, head); output bf16 aob ----------------
__global__ __launch_bounds__(256) void k_attn(const float* __restrict__ q, const float* __restrict__ k,
                                              const float* __restrict__ v, unsigned short* __restrict__ aob){
    __shared__ float Qs[1600], Ks[1600], Vs[1600], Sc[2500];
    int t = threadIdx.x;
    int s = blockIdx.x >> 2; int hh = blockIdx.x & 3;
    for (int idx=t; idx<1600; idx+=256){
        int i = idx>>5, d = idx&31;
        size_t gi = (size_t)(s*50+i)*F + hh*32 + d;
        Qs[idx]=q[gi]; Ks[idx]=k[gi]; Vs[idx]=v[gi];
    }
    __syncthreads();
    for (int idx=t; idx<2500; idx+=256){
        int qi = idx/50, ki = idx%50;
        float acc=0.f;
        #pragma unroll 8
        for (int d=0;d<32;d++) acc += Qs[qi*32+d]*Ks[ki*32+d];
        Sc[idx] = acc * 0.17677669529663687f;   // 1/sqrt(32)
    }
    __syncthreads();
    if (t < 50){
        float m=-1e30f;
        for (int j=0;j<50;j++) m = fmaxf(m, Sc[t*50+j]);
        float sum=0.f;
        for (int j=0;j<50;j++){ float e=__expf(Sc[t*50+j]-m); Sc[t*50+j]=e; sum+=e; }
        float inv = 1.f/sum;
        for (int j=0;j<50;j++) Sc[t*50+j] *= inv;
    }
    __syncthreads();
    for (int idx=t; idx<1600; idx+=256){
        int qi = idx>>5, d = idx&31;
        float acc=0.f;
        #pragma unroll 10
        for (int ki=0;ki<50;ki++) acc += Sc[qi*50+ki]*Vs[ki*32+d];
        aob[(size_t)(s*50+qi)*F + hh*32 + d] = (unsigned short)f2bs(acc);
    }
}

// ---------------- fused post-attention: Wo+LN1 -> FFN1 -> FFN2 -> LN2+gsi ----------------
// 125 blocks x 16 rows; 4 waves split cols/K; row-wide LNs via 16-threads-per-row shfl.
// LDS: zd1f f32[16][132]; zd1b bf16[16][136]; f1b bf16[16][1040]; zd2b bf16[16][136].
__global__ __launch_bounds__(256) void k_post(const unsigned short* __restrict__ aob,
                                              const float* __restrict__ z,
                                              const unsigned short* __restrict__ Wob, const float* __restrict__ bo,
                                              const float* __restrict__ ln1_g, const float* __restrict__ ln1_b,
                                              const unsigned short* __restrict__ W1b, const float* __restrict__ b1,
                                              const unsigned short* __restrict__ W2b, const float* __restrict__ b2,
                                              const float* __restrict__ ln2_g, const float* __restrict__ ln2_b,
                                              const unsigned short* __restrict__ Wgbotb, const float* __restrict__ bg,
                                              float* __restrict__ zd2, float* __restrict__ gsi){
    __shared__ float zd1f[16*132];
    __shared__ short zd1b[16*136];
    __shared__ short f1b[16*1040];
    __shared__ short zd2b[16*136];
    int t = threadIdx.x;
    int lane = t & 63, w = t >> 6;
    int lr = lane & 15, quad = lane >> 4;
    int gr0 = blockIdx.x * 16;

    // ---- stage A: Wo projection (wave w -> col-tiles 2w,2w+1) ----
    {
        f32x4 accA[2];
        accA[0] = (f32x4){0.f,0.f,0.f,0.f};
        accA[1] = (f32x4){0.f,0.f,0.f,0.f};
        #pragma unroll
        for (int ks4=0; ks4<4; ++ks4){
            int kb = ks4*32 + quad*8;
            short8 a = *(const short8*)&aob[(size_t)(gr0 + lr)*F + kb];
            #pragma unroll
            for (int j=0;j<2;j++){
                int nt = 2*w + j;
                short8 b = *(const short8*)&Wob[(size_t)(nt*16 + lr)*128 + kb];
                accA[j] = __builtin_amdgcn_mfma_f32_16x16x32_bf16(a, b, accA[j], 0, 0, 0);
            }
        }
        #pragma unroll
        for (int j=0;j<2;j++){
            int nt = 2*w + j;
            #pragma unroll
            for (int r=0;r<4;r++){
                int row = quad*4 + r;
                int col = nt*16 + lr;
                zd1f[row*132 + col] = accA[j][r] + bo[col] + z[(size_t)(gr0+row)*F + col];
            }
        }
    }
    __syncthreads();
    // ---- LN1: 16 threads per row ----
    {
        int tr = t >> 4, l16 = t & 15;
        float v[8];
        #pragma unroll
        for (int i=0;i<8;i++) v[i] = zd1f[tr*132 + l16*8 + i];
        float s = 0.f;
        #pragma unroll
        for (int i=0;i<8;i++) s += v[i];
        #pragma unroll
        for (int off=1; off<16; off<<=1) s += __shfl_xor(s, off);
        float mean = s * (1.f/128.f);
        float var = 0.f;
        float d[8];
        #pragma unroll
        for (int i=0;i<8;i++){ d[i] = v[i]-mean; var += d[i]*d[i]; }
        #pragma unroll
        for (int off=1; off<16; off<<=1) var += __shfl_xor(var, off);
        float rsv = rsqrtf(var*(1.f/128.f) + 1e-5f);
        #pragma unroll
        for (int i=0;i<8;i++){
            int c = l16*8 + i;
            float o = d[i]*rsv*ln1_g[c] + ln1_b[c];
            zd1f[tr*132 + c] = o;
            zd1b[tr*136 + c] = f2bs(o);
        }
    }
    __syncthreads();

    // ---- stage B: FFN1 (wave w -> cols [256w, 256w+256)) ----
    {
        short8 a[4];
        #pragma unroll
        for (int ks4=0; ks4<4; ++ks4){
            int kb = ks4*32 + quad*8;
            a[ks4] = *(const short8*)&zd1b[lr*136 + kb];
        }
        for (int nt2=0; nt2<16; ++nt2){
            int coln = w*256 + nt2*16 + lr;
            f32x4 acc = (f32x4){0.f,0.f,0.f,0.f};
            #pragma unroll
            for (int ks4=0; ks4<4; ++ks4){
                int kb = ks4*32 + quad*8;
                short8 b = *(const short8*)&W1b[(size_t)coln*128 + kb];
                acc = __builtin_amdgcn_mfma_f32_16x16x32_bf16(a[ks4], b, acc, 0, 0, 0);
            }
            #pragma unroll
            for (int r=0;r<4;r++){
                int row = quad*4 + r;
                int col = w*256 + nt2*16 + lr;
                f1b[row*1040 + col] = f2bs(fmaxf(acc[r] + b1[col], 0.f));
            }
        }
    }
    __syncthreads();

    // ---- stage C: FFN2 (wave w -> col-tiles 2w,2w+1; full K=1024 in registers) ----
    f32x4 accC[2];
    accC[0] = (f32x4){0.f,0.f,0.f,0.f};
    accC[1] = (f32x4){0.f,0.f,0.f,0.f};
    for (int ks4=0; ks4<32; ++ks4){
        int kb = ks4*32 + quad*8;
        short8 a = *(const short8*)&f1b[lr*1040 + kb];
        #pragma unroll
        for (int j=0;j<2;j++){
            int nt = 2*w + j;
            short8 b = *(const short8*)&W2b[(size_t)(nt*16 + lr)*1024 + kb];
            accC[j] = __builtin_amdgcn_mfma_f32_16x16x32_bf16(a, b, accC[j], 0, 0, 0);
        }
    }
    // pre-LN2 values back into zd1f (each lane overwrites exactly what it owns)
    #pragma unroll
    for (int j=0;j<2;j++){
        int nt = 2*w + j;
        #pragma unroll
        for (int r=0;r<4;r++){
            int row = quad*4 + r;
            int col = nt*16 + lr;
            zd1f[row*132 + col] = accC[j][r] + b2[col] + zd1f[row*132 + col];
        }
    }
    __syncthreads();
    // ---- LN2 + zd2 write ----
    {
        int tr = t >> 4, l16 = t & 15;
        float v[8];
        #pragma unroll
        for (int i=0;i<8;i++) v[i] = zd1f[tr*132 + l16*8 + i];
        float s = 0.f;
        #pragma unroll
        for (int i=0;i<8;i++) s += v[i];
        #pragma unroll
        for (int off=1; off<16; off<<=1) s += __shfl_xor(s, off);
        float mean = s * (1.f/128.f);
        float var = 0.f;
        float d[8];
        #pragma unroll
        for (int i=0;i<8;i++){ d[i] = v[i]-mean; var += d[i]*d[i]; }
        #pragma unroll
        for (int off=1; off<16; off<<=1) var += __shfl_xor(var, off);
        float rsv = rsqrtf(var*(1.f/128.f) + 1e-5f);
        #pragma unroll
        for (int i=0;i<8;i++){
            int c = l16*8 + i;
            float o = d[i]*rsv*ln2_g[c] + ln2_b[c];
            zd2[(size_t)(gr0+tr)*F + c] = o;
            zd2b[tr*136 + c] = f2bs(o);
        }
    }
    __syncthreads();
    // ---- gsi = zd2 @ Wg_bot + bg ----
    {
        f32x4 accG[2];
        accG[0] = (f32x4){0.f,0.f,0.f,0.f};
        accG[1] = (f32x4){0.f,0.f,0.f,0.f};
        #pragma unroll
        for (int ks4=0; ks4<4; ++ks4){
            int kb = ks4*32 + quad*8;
            short8 a = *(const short8*)&zd2b[lr*136 + kb];
            #pragma unroll
            for (int j=0;j<2;j++){
                int nt = 2*w + j;
                short8 b = *(const short8*)&Wgbotb[(size_t)(nt*16 + lr)*128 + kb];
                accG[j] = __builtin_amdgcn_mfma_f32_16x16x32_bf16(a, b, accG[j], 0, 0, 0);
            }
        }
        #pragma unroll
        for (int j=0;j<2;j++){
            int nt = 2*w + j;
            #pragma unroll
            for (int r=0;r<4;r++){
                int row = quad*4 + r;
                int col = nt*16 + lr;
                gsi[(size_t)(gr0+row)*F + col] = accG[j][r] + bg[col];
            }
        }
    }
}

// ---------------- MFMA gate: 64-row tiles, B from global bf16 Wgb (no LDS, no barriers) ----------------
__global__ __launch_bounds__(256) void k_gate_mfma(const float* __restrict__ h,
                                                   const unsigned short* __restrict__ hb,
                                                   const unsigned short* __restrict__ Wgb,
                                                   const float* __restrict__ gsi, const float* __restrict__ zd2,
                                                   float* __restrict__ out){
    int t = threadIdx.x;
    int lane = t & 63, w = t >> 6;
    int lr = lane & 15, quad = lane >> 4;
    int mrow0 = blockIdx.x*64 + w*16;
    f32x4 acc[8];
    #pragma unroll
    for (int j=0;j<8;j++) acc[j] = (f32x4){0.f,0.f,0.f,0.f};
    #pragma unroll
    for (int ks=0; ks<4; ++ks){
        int kb = ks*32 + quad*8;
        int row = mrow0 + lr;
        if (row >= NN) row = NN-1;
        short8 a = *(const short8*)&hb[(size_t)row*F + kb];
        #pragma unroll
        for (int nt=0; nt<8; ++nt){
            short8 b = *(const short8*)&Wgb[(size_t)(nt*16 + lr)*128 + kb];
            acc[nt] = __builtin_amdgcn_mfma_f32_16x16x32_bf16(a, b, acc[nt], 0, 0, 0);
        }
    }
    #pragma unroll
    for (int r=0; r<4; ++r){
        int row = mrow0 + quad*4 + r;
        if (row >= NN) continue;
        int g = row / 50;
        const float* gs = &gsi[(size_t)g*F];
        const float* zs = &zd2[(size_t)g*F];
        const float* hr = &h[(size_t)row*F];
        float* orow = &out[(size_t)row*F];
        #pragma unroll
        for (int nt=0; nt<8; ++nt){
            int col = nt*16 + lr;
            float L = acc[nt][r] + gs[col];
            float gate = 1.f/(1.f + __expf(-L));
            orow[col] = gate*zs[col] + (1.f-gate)*hr[col];
        }
    }
}

extern "C" void kernel_launch(void* const* d_in, const int* in_sizes, int n_in,
                              void* d_out, int out_size, void* d_ws, size_t ws_size,
                              hipStream_t stream) {
    const float* x      = (const float*)d_in[0];
    const int*   ei     = (const int*)d_in[1];
    const float* W_gcn  = (const float*)d_in[4];
    const float* b_gcn  = (const float*)d_in[5];
    const float* bn_g   = (const float*)d_in[6];
    const float* bn_b   = (const float*)d_in[7];
    const float* lnpre_g= (const float*)d_in[8];
    const float* lnpre_b= (const float*)d_in[9];
    const float* Wq     = (const float*)d_in[10];
    const float* bq     = (const float*)d_in[11];
    const float* Wk     = (const float*)d_in[12];
    const float* bk     = (const float*)d_in[13];
    const float* Wv     = (const float*)d_in[14];
    const float* bv     = (const float*)d_in[15];
    const float* Wo     = (const float*)d_in[16];
    const float* bo     = (const float*)d_in[17];
    const float* ln1_g  = (const float*)d_in[18];
    const float* ln1_b  = (const float*)d_in[19];
    const float* W1     = (const float*)d_in[20];
    const float* b1     = (const float*)d_in[21];
    const float* W2     = (const float*)d_in[22];
    const float* b2     = (const float*)d_in[23];
    const float* ln2_g  = (const float*)d_in[24];
    const float* ln2_b  = (const float*)d_in[25];
    const float* Wg     = (const float*)d_in[26];
    const float* bg     = (const float*)d_in[27];
    float* out = (float*)d_out;
    char* ws = (char*)d_ws;

    // workspace layout
    size_t o = 0;
    unsigned char* xws8 = (unsigned char*)(ws + o); o += (size_t)NN*F; // 12.8 MB (fp8)
    float* h     = (float*)(ws + o); o += (size_t)NN*F*4;            // 51.2 MB
    unsigned short* hb = (unsigned short*)(ws + o); o += (size_t)NN*F*2; // 25.6 MB (bf16)
    int*   cnt   = (int*)(ws + o);   o += (size_t)NN*4;
    int*   nstart= (int*)(ws + o);   o += (size_t)NN*4;
    int*   ebuf  = (int*)(ws + o);   o += (size_t)NB*BCAP*4;         // 9.6 MB
    int*   ebuf2 = (int*)(ws + o);   o += (size_t)NB*BCAP*4;         // 9.6 MB
    float* dinv  = (float*)(ws + o); o += (size_t)NN*4;
    int*   bcursor=(int*)(ws + o);   o += 1024*4;
    unsigned short* Wgb    = (unsigned short*)(ws + o); o += 16384*2;
    unsigned short* Wob    = (unsigned short*)(ws + o); o += 16384*2;
    unsigned short* Wgbotb = (unsigned short*)(ws + o); o += 16384*2;
    unsigned short* W1b = (unsigned short*)(ws + o); o += (size_t)131072*2;  // 256 KB
    unsigned short* W2b = (unsigned short*)(ws + o); o += (size_t)131072*2;  // 256 KB
    float* z     = (float*)(ws + o); o += (size_t)NG*F*4;
    float* qb    = (float*)(ws + o); o += (size_t)NG*F*4;
    float* kb2   = (float*)(ws + o); o += (size_t)NG*F*4;
    float* vb    = (float*)(ws + o); o += (size_t)NG*F*4;
    unsigned short* aob = (unsigned short*)(ws + o); o += (size_t)NG*F*2;
    float* zd2   = (float*)(ws + o); o += (size_t)NG*F*4;
    float* gsi   = (float*)(ws + o); o += (size_t)NG*F*4;

    // ---- GCN phase ----
    hipMemsetAsync(bcursor, 0, (size_t)NB*4, stream);
    k_scatter2<<<SC_BLOCKS, 1024, 0, stream>>>(ei, bcursor, ebuf);
    k_sort<<<NB, 256, 0, stream>>>(ebuf, bcursor, cnt, dinv, nstart, ebuf2);
    k_xws<<<NXB + NWB, 256, 0, stream>>>(x, W_gcn, dinv, xws8,
                                         Wo, W1, W2, Wg,
                                         Wob, W1b, W2b, Wgb, Wgbotb);
    k_aggpool<<<NG, 256, 0, stream>>>(xws8, nstart, cnt, dinv, b_gcn, bn_g, bn_b, ebuf2,
                                      lnpre_g, lnpre_b, Wq, bq, Wk, bk, Wv, bv,
                                      h, hb, z, qb, kb2, vb);

    // ---- set transformer: attn + fused row-local post chain ----
    k_attn<<<NS*4, 256, 0, stream>>>(qb, kb2, vb, aob);
    k_post<<<NG/16, 256, 0, stream>>>(aob, z, Wob, bo, ln1_g, ln1_b, W1b, b1,
                                      W2b, b2, ln2_g, ln2_b, Wgbotb, bg, zd2, gsi);

    // ---- gated fusion -> output ----
    k_gate_mfma<<<(NN+63)/64, 256, 0, stream>>>(h, hb, Wgb, gsi, zd2, out);
}